// Round 14
// baseline (825.353 us; speedup 1.0000x reference)
//
#include <hip/hip_runtime.h>
#include <math.h>

#define HD 256
#define NEG 0.2f
#define BN_EPS 1e-5f
#define GSTAT 256  // deterministic BN partial blocks
#define APAD 8

typedef __attribute__((ext_vector_type(8))) short short8v;   // 8 bf16 (4 VGPRs)
typedef __attribute__((ext_vector_type(4))) float f32x4;     // MFMA accumulator

__device__ __forceinline__ ushort bf16_rn(float x) {
  unsigned u = __float_as_uint(x);
  return (ushort)((u + 0x7FFFu + ((u >> 16) & 1u)) >> 16);
}
__device__ __forceinline__ float bf16_to_f(ushort b) {
  return __uint_as_float(((unsigned)b) << 16);
}

// ---------------- CSR build (by dst) ----------------
__global__ void hist_kernel(const int* __restrict__ dst, int* __restrict__ cnt, int E) {
  int i = blockIdx.x * blockDim.x + threadIdx.x;
  if (i < E) atomicAdd(&cnt[dst[i]], 1);
}

__global__ __launch_bounds__(1024) void scan_kernel(const int* __restrict__ cnt,
                                                    int* __restrict__ rowptr, int n) {
  __shared__ int sdata[1024];
  int t = threadIdx.x;
  int ipt = (n + 1023) >> 10;
  int base = t * ipt;
  int s = 0;
  for (int i = 0; i < ipt; ++i) { int idx = base + i; if (idx < n) s += cnt[idx]; }
  sdata[t] = s;
  __syncthreads();
  for (int off = 1; off < 1024; off <<= 1) {
    int v = (t >= off) ? sdata[t - off] : 0;
    __syncthreads();
    sdata[t] += v;
    __syncthreads();
  }
  int run = (t == 0) ? 0 : sdata[t - 1];
  for (int i = 0; i < ipt; ++i) {
    int idx = base + i;
    if (idx < n) { run += cnt[idx]; rowptr[idx + 1] = run; }
  }
  if (t == 0) rowptr[0] = 0;
}

__global__ void scatter_kernel(const int* __restrict__ dst, const int* __restrict__ rowptr,
                               int* __restrict__ fill, int* __restrict__ esort, int E) {
  int i = blockIdx.x * blockDim.x + threadIdx.x;
  if (i < E) {
    int d = dst[i];
    int pos = atomicAdd(&fill[d], 1);
    esort[rowptr[d] + pos] = i;
  }
}

// ---------------- per-node sort + CSR-ordered index/edge-attr materialization ----------------
__global__ __launch_bounds__(256) void csr_finish(const int* __restrict__ src,
                                                  const int* __restrict__ rowptr,
                                                  const int* __restrict__ esort,
                                                  const float* __restrict__ ea,
                                                  int* __restrict__ esrc,
                                                  float* __restrict__ eac, int n) {
  int t = threadIdx.x;
  int lane = t & 63;
  int node = __builtin_amdgcn_readfirstlane(blockIdx.x * 4 + (t >> 6));
  if (node >= n) return;
  int pbeg = rowptr[node], pend = rowptr[node + 1];
  int deg = pend - pbeg;
  if (deg == 0 || deg > 64) return;
  int v = (lane < deg) ? esort[pbeg + lane] : 0x7fffffff;
#pragma unroll
  for (int k = 2; k <= 64; k <<= 1) {
#pragma unroll
    for (int j = k >> 1; j >= 1; j >>= 1) {
      int u = __shfl_xor(v, j);
      bool keepmin = (((lane & k) == 0) == ((lane & j) == 0));
      v = keepmin ? (v < u ? v : u) : (v > u ? v : u);
    }
  }
  if (lane < deg) {
    esrc[pbeg + lane] = src[v];
    const float4* s4 = (const float4*)(ea + (size_t)v * 16);
    float4* d4 = (float4*)(eac + (size_t)(pbeg + lane) * 16);
    d4[0] = s4[0]; d4[1] = s4[1]; d4[2] = s4[2]; d4[3] = s4[3];
  }
}

// ---------------- dual GEMM K=6 (layer 0) ----------------
__global__ __launch_bounds__(256) void gemm_dual6(const float* __restrict__ h,
                                                  const float* __restrict__ Wl,
                                                  const float* __restrict__ Wr,
                                                  float* __restrict__ xlo, float* __restrict__ xro,
                                                  int n) {
  __shared__ float hs[32 * 6];
  int r0 = blockIdx.x * 32;
  int t = threadIdx.x;
  int nr = min(32, n - r0);
  int tot = nr * 6;
  for (int i = t; i < tot; i += 256) hs[i] = h[(size_t)r0 * 6 + i];
  __syncthreads();
  float accl[32], accr[32];
#pragma unroll
  for (int r = 0; r < 32; ++r) { accl[r] = 0.f; accr[r] = 0.f; }
  int j = t;
  for (int k = 0; k < 6; ++k) {
    float wl = Wl[k * HD + j];
    float wr = Wr[k * HD + j];
#pragma unroll
    for (int r = 0; r < 32; ++r) {
      float hv = hs[r * 6 + k];
      accl[r] += hv * wl;
      accr[r] += hv * wr;
    }
  }
  for (int r = 0; r < nr; ++r) {
    xlo[(size_t)(r0 + r) * HD + j] = accl[r];
    xro[(size_t)(r0 + r) * HD + j] = accr[r];
  }
}

// ---------------- weight split+transpose (once per layer): Wt[j][k] hi/lo bf16 ----------------
__global__ __launch_bounds__(256) void split_w(const float* __restrict__ Wl,
                                               const float* __restrict__ Wr,
                                               ushort* __restrict__ wthi,
                                               ushort* __restrict__ wtlo) {
  int idx = blockIdx.x * 256 + threadIdx.x;  // 512*256
  int j = idx >> 8;
  int k = idx & 255;
  float v = (j < 256) ? Wl[k * 256 + j] : Wr[k * 256 + (j - 256)];
  ushort hi = bf16_rn(v);
  float lo = v - bf16_to_f(hi);
  wthi[idx] = hi;
  wtlo[idx] = bf16_rn(lo);
}

// ---------------- BN finalize (deterministic, 1 block) ----------------
__global__ void bn_finalize(const float* __restrict__ partials, const float* __restrict__ gamma,
                            const float* __restrict__ beta, float* __restrict__ ss, float nf) {
  int c = threadIdx.x;
  float s = 0.f, s2 = 0.f;
  for (int g = 0; g < GSTAT; ++g) {
    s += partials[g * 512 + c];
    s2 += partials[g * 512 + 256 + c];
  }
  float mean = s / nf;
  float var = s2 / nf - mean * mean;
  float sc = gamma[c] * rsqrtf(var + BN_EPS);
  ss[c] = sc;
  ss[256 + c] = beta[c] - mean * sc;
}

// ---------------- BN+ReLU apply + hi/lo bf16 split (vectorized x4) ----------------
__global__ __launch_bounds__(256) void bn_convert(const float4* __restrict__ h,
                                                  const float* __restrict__ ss,
                                                  ushort4* __restrict__ hhi,
                                                  ushort4* __restrict__ hlo, int total4) {
  int i = blockIdx.x * 256 + threadIdx.x;
  if (i >= total4) return;
  int c = (i & 63) * 4;
  float4 v = h[i];
  float a0 = fmaxf(v.x * ss[c + 0] + ss[256 + c + 0], 0.f);
  float a1 = fmaxf(v.y * ss[c + 1] + ss[256 + c + 1], 0.f);
  float a2 = fmaxf(v.z * ss[c + 2] + ss[256 + c + 2], 0.f);
  float a3 = fmaxf(v.w * ss[c + 3] + ss[256 + c + 3], 0.f);
  ushort4 hi, lo;
  hi.x = bf16_rn(a0); lo.x = bf16_rn(a0 - bf16_to_f(hi.x));
  hi.y = bf16_rn(a1); lo.y = bf16_rn(a1 - bf16_to_f(hi.y));
  hi.z = bf16_rn(a2); lo.z = bf16_rn(a2 - bf16_to_f(hi.z));
  hi.w = bf16_rn(a3); lo.w = bf16_rn(a3 - bf16_to_f(hi.w));
  hhi[i] = hi;
  hlo[i] = lo;
}

// ---------------- MFMA GEMM, full-N tile: block = 16 rows x 512 cols ----------------
__global__ __launch_bounds__(256) void gemm_mfma(const ushort* __restrict__ hhi,
                                                 const ushort* __restrict__ hlo,
                                                 const ushort* __restrict__ wthi,
                                                 const ushort* __restrict__ wtlo,
                                                 float* __restrict__ xlo_,
                                                 float* __restrict__ xro_, int n) {
  __shared__ ushort Ahi[16][256 + APAD];
  __shared__ ushort Alo[16][256 + APAD];
  int t = threadIdx.x;
  int r0 = blockIdx.x * 16;
  if (r0 >= n) return;
  {
    const ushort4* ghi = (const ushort4*)(hhi + (size_t)r0 * 256);
    const ushort4* glo = (const ushort4*)(hlo + (size_t)r0 * 256);
    for (int i = t; i < 1024; i += 256) {
      int row = i >> 6, c4 = (i & 63) * 4;
      ushort4 v = ghi[i];
      *(ushort4*)&Ahi[row][c4] = v;
      ushort4 u = glo[i];
      *(ushort4*)&Alo[row][c4] = u;
    }
  }
  __syncthreads();
  int wid = t >> 6, lane = t & 63;
  int lr = lane & 15, lk = lane >> 4;
  int cbase = wid * 128;
  f32x4 acc[8];
#pragma unroll
  for (int f = 0; f < 8; ++f) acc[f] = (f32x4){0.f, 0.f, 0.f, 0.f};
#pragma unroll
  for (int kk = 0; kk < 8; ++kk) {
    int ko = kk * 32 + lk * 8;
    short8v ahi = *(const short8v*)&Ahi[lr][ko];
    short8v alo = *(const short8v*)&Alo[lr][ko];
#pragma unroll
    for (int f = 0; f < 8; ++f) {
      size_t cc = (size_t)(cbase + f * 16 + lr);
      short8v bhi = *(const short8v*)(wthi + cc * 256 + ko);
      short8v blo = *(const short8v*)(wtlo + cc * 256 + ko);
      acc[f] = __builtin_amdgcn_mfma_f32_16x16x32_bf16(ahi, bhi, acc[f], 0, 0, 0);
      acc[f] = __builtin_amdgcn_mfma_f32_16x16x32_bf16(ahi, blo, acc[f], 0, 0, 0);
      acc[f] = __builtin_amdgcn_mfma_f32_16x16x32_bf16(alo, bhi, acc[f], 0, 0, 0);
    }
  }
#pragma unroll
  for (int f = 0; f < 8; ++f) {
    int cc = cbase + f * 16 + lr;
    float* outp = (cc < 256) ? (xlo_ + cc) : (xro_ + (cc - 256));
#pragma unroll
    for (int j = 0; j < 4; ++j)
      outp[(size_t)(r0 + lk * 4 + j) * 256] = acc[f][j];
  }
}

// ---------------- fused GATv2 layer: 1 wave = 1 node, We pinned in VGPRs ----------------
// 8-edge gather batches: 8 independent 1KB row-gathers in flight per iteration (R13:
// VALUBusy 46% / occupancy 35% -> latency-limited; more MLP per wave). VGPR ~72-88 < 128.
__global__ __launch_bounds__(64, 4) void gat_kernel(const float* __restrict__ xl,
                                                    const float* __restrict__ xr,
                                                    const int* __restrict__ esrc,
                                                    const float* __restrict__ eac,
                                                    const int* __restrict__ esort,
                                                    const int* __restrict__ src,
                                                    const float* __restrict__ ea,
                                                    const int* __restrict__ rowptr,
                                                    const float* __restrict__ We,
                                                    const float* __restrict__ att,
                                                    const float* __restrict__ bc,
                                                    float* __restrict__ hout, int n) {
  int lane = threadIdx.x;
  int node = blockIdx.x;
  if (node >= n) return;
  int c = lane * 4;
  size_t nb = (size_t)node * HD;
  float4 bc4 = *(const float4*)(bc + c);
  int pbeg = rowptr[node], pend = rowptr[node + 1];
  int deg = pend - pbeg;
  if (deg == 0) { *(float4*)(hout + nb + c) = bc4; return; }

  float4 w4[16];
#pragma unroll
  for (int k = 0; k < 16; ++k) w4[k] = *(const float4*)(We + k * HD + c);
#pragma unroll
  for (int k = 0; k < 16; ++k)
    asm volatile("" : "+v"(w4[k].x), "+v"(w4[k].y), "+v"(w4[k].z), "+v"(w4[k].w));

  float4 att4 = *(const float4*)(att + c);
  float4 xr4 = *(const float4*)(xr + nb + c);
  float4 acc = make_float4(0.f, 0.f, 0.f, 0.f);
  float m = -3.0e38f, d = 0.f;

  if (deg <= 64) {
    int es = (lane < deg) ? esrc[pbeg + lane] : 0;
    for (int b = 0; b < deg; b += 8) {
      int nbt = min(8, deg - b);
      float4 xv[8];
#pragma unroll
      for (int i = 0; i < 8; ++i) {
        if (i < nbt) {
          int si = __builtin_amdgcn_readfirstlane(__shfl(es, b + i));
          xv[i] = *(const float4*)(xl + (size_t)si * HD + c);
        }
      }
#pragma unroll
      for (int i = 0; i < 8; ++i) {
        if (i < nbt) {
          const float* ear = eac + (size_t)(pbeg + b + i) * 16;  // uniform -> s_load
          float4 v;
          v.x = xv[i].x + xr4.x;
          v.y = xv[i].y + xr4.y;
          v.z = xv[i].z + xr4.z;
          v.w = xv[i].w + xr4.w;
#pragma unroll
          for (int k = 0; k < 16; ++k) {
            float av = ear[k];
            v.x += av * w4[k].x;
            v.y += av * w4[k].y;
            v.z += av * w4[k].z;
            v.w += av * w4[k].w;
          }
          // leaky_relu(x) = max(x, NEG*x) for 0<NEG<1
          float l0 = fmaxf(v.x, NEG * v.x);
          float l1 = fmaxf(v.y, NEG * v.y);
          float l2 = fmaxf(v.z, NEG * v.z);
          float l3 = fmaxf(v.w, NEG * v.w);
          float pv = l0 * att4.x + l1 * att4.y + l2 * att4.z + l3 * att4.w;
          pv += __shfl_xor(pv, 16);
          pv += __shfl_xor(pv, 8);
          pv += __shfl_xor(pv, 4);
          pv += __shfl_xor(pv, 2);
          pv += __shfl_xor(pv, 1);
          float rs, pe;
          if (pv > m) { rs = __expf(m - pv); m = pv; pe = 1.f; }
          else        { rs = 1.f; pe = __expf(pv - m); }
          d = d * rs + pe;
          acc.x = acc.x * rs + pe * xv[i].x;
          acc.y = acc.y * rs + pe * xv[i].y;
          acc.z = acc.z * rs + pe * xv[i].z;
          acc.w = acc.w * rs + pe * xv[i].w;
        }
      }
    }
  } else {
    int last = -1;
    for (int r = 0; r < deg; ++r) {
      int mymin = 0x7fffffff;
      for (int p = pbeg + lane; p < pend; p += 64) {
        int v = esort[p];
        mymin = (v > last && v < mymin) ? v : mymin;
      }
#pragma unroll
      for (int off = 32; off >= 1; off >>= 1) {
        int u = __shfl_xor(mymin, off);
        mymin = min(mymin, u);
      }
      int e = __builtin_amdgcn_readfirstlane(mymin);
      last = e;
      int s = __builtin_amdgcn_readfirstlane(src[e]);
      float4 xv = *(const float4*)(xl + (size_t)s * HD + c);
      const float* ear = ea + (size_t)e * 16;
      float4 v;
      v.x = xv.x + xr4.x; v.y = xv.y + xr4.y; v.z = xv.z + xr4.z; v.w = xv.w + xr4.w;
#pragma unroll
      for (int k = 0; k < 16; ++k) {
        float av = ear[k];
        v.x += av * w4[k].x;
        v.y += av * w4[k].y;
        v.z += av * w4[k].z;
        v.w += av * w4[k].w;
      }
      float l0 = fmaxf(v.x, NEG * v.x);
      float l1 = fmaxf(v.y, NEG * v.y);
      float l2 = fmaxf(v.z, NEG * v.z);
      float l3 = fmaxf(v.w, NEG * v.w);
      float pv = l0 * att4.x + l1 * att4.y + l2 * att4.z + l3 * att4.w;
      pv += __shfl_xor(pv, 16);
      pv += __shfl_xor(pv, 8);
      pv += __shfl_xor(pv, 4);
      pv += __shfl_xor(pv, 2);
      pv += __shfl_xor(pv, 1);
      float rs, pe;
      if (pv > m) { rs = __expf(m - pv); m = pv; pe = 1.f; }
      else        { rs = 1.f; pe = __expf(pv - m); }
      d = d * rs + pe;
      acc.x = acc.x * rs + pe * xv.x;
      acc.y = acc.y * rs + pe * xv.y;
      acc.z = acc.z * rs + pe * xv.z;
      acc.w = acc.w * rs + pe * xv.w;
    }
  }
  float inv = d > 0.f ? 1.f / d : 0.f;
  float4 o;
  o.x = acc.x * inv + bc4.x;
  o.y = acc.y * inv + bc4.y;
  o.z = acc.z * inv + bc4.z;
  o.w = acc.w * inv + bc4.w;
  *(float4*)(hout + nb + c) = o;
}

// ---------------- deterministic BN partials ----------------
__global__ __launch_bounds__(256) void bn_stats(const float* __restrict__ h,
                                                float* __restrict__ partials, int n) {
  int c = threadIdx.x;
  int g = blockIdx.x;
  int rows = (n + GSTAT - 1) / GSTAT;
  int r0 = g * rows;
  int r1 = min(n, r0 + rows);
  float s = 0.f, s2 = 0.f;
  for (int r = r0; r < r1; ++r) {
    float v = h[(size_t)r * HD + c];
    s += v;
    s2 += v * v;
  }
  partials[g * 512 + c] = s;
  partials[g * 512 + 256 + c] = s2;
}

// ---------------- fused head: BN+ReLU + mean-pool + 3-layer MLP ----------------
__global__ __launch_bounds__(256) void head_kernel(const float* __restrict__ h,
                                                   const float* __restrict__ partials,
                                                   const float* __restrict__ gamma,
                                                   const float* __restrict__ beta,
                                                   const int* __restrict__ batch,
                                                   const float* __restrict__ gf,
                                                   const float* __restrict__ W1,
                                                   const float* __restrict__ b1,
                                                   const float* __restrict__ W2,
                                                   const float* __restrict__ b2,
                                                   const float* __restrict__ W3,
                                                   const float* __restrict__ b3,
                                                   float* __restrict__ out, int n, float nf) {
  int b = blockIdx.x, t = threadIdx.x;
  float s = 0.f, s2 = 0.f;
  for (int g = 0; g < GSTAT; ++g) {
    s += partials[g * 512 + t];
    s2 += partials[g * 512 + 256 + t];
  }
  float mean = s / nf;
  float var = s2 / nf - mean * mean;
  float sc = gamma[t] * rsqrtf(var + BN_EPS);
  float sh = beta[t] - mean * sc;

  int lo = 0, hi = n;
  while (lo < hi) { int mid = (lo + hi) >> 1; if (batch[mid] < b) lo = mid + 1; else hi = mid; }
  int s0 = lo;
  lo = 0; hi = n;
  while (lo < hi) { int mid = (lo + hi) >> 1; if (batch[mid] < b + 1) lo = mid + 1; else hi = mid; }
  int s1 = lo;

  float acc = 0.f;
  for (int r = s0; r < s1; ++r) acc += fmaxf(h[(size_t)r * HD + t] * sc + sh, 0.f);

  __shared__ float in_s[264];
  __shared__ float z1s[256];
  __shared__ float z2s[128];
  float cnt = (float)(s1 - s0);
  in_s[t] = (s1 > s0) ? acc / cnt : 0.f;
  if (t < 8) in_s[HD + t] = gf[b * 8 + t];
  __syncthreads();
  float z = b1[t];
  for (int k = 0; k < 264; ++k) z += in_s[k] * W1[(size_t)k * 256 + t];
  z1s[t] = fmaxf(z, 0.f);
  __syncthreads();
  if (t < 128) {
    float a2 = b2[t];
    for (int k = 0; k < 256; ++k) a2 += z1s[k] * W2[k * 128 + t];
    z2s[t] = fmaxf(a2, 0.f);
  }
  __syncthreads();
  if (t < 100) {
    float o = b3[t];
    for (int k = 0; k < 128; ++k) o += z2s[k] * W3[k * 100 + t];
    out[b * 100 + t] = o;
  }
}

extern "C" void kernel_launch(void* const* d_in, const int* in_sizes, int n_in,
                              void* d_out, int out_size, void* d_ws, size_t ws_size,
                              hipStream_t stream) {
  (void)n_in; (void)out_size; (void)ws_size;
  const float* x      = (const float*)d_in[0];
  const int*   ei     = (const int*)d_in[1];
  const float* ea     = (const float*)d_in[2];
  const int*   batch  = (const int*)d_in[3];
  const float* gf     = (const float*)d_in[4];
  const int E = in_sizes[1] / 2;
  const int N = in_sizes[3];
  const int B = in_sizes[4] / 8;
  const int* srcA = ei;
  const int* dstA = ei + E;

  const float *Wl[3], *Wr[3], *We[3], *att[3], *bc[3], *gamma[3], *beta[3];
  for (int l = 0; l < 3; ++l) {
    int base = 5 + 7 * l;
    Wl[l]    = (const float*)d_in[base + 0];
    Wr[l]    = (const float*)d_in[base + 1];
    We[l]    = (const float*)d_in[base + 2];
    att[l]   = (const float*)d_in[base + 3];
    bc[l]    = (const float*)d_in[base + 4];
    gamma[l] = (const float*)d_in[base + 5];
    beta[l]  = (const float*)d_in[base + 6];
  }
  const float* W1 = (const float*)d_in[26];
  const float* b1 = (const float*)d_in[27];
  const float* W2 = (const float*)d_in[28];
  const float* b2 = (const float*)d_in[29];
  const float* W3 = (const float*)d_in[30];
  const float* b3 = (const float*)d_in[31];

  char* w = (char*)d_ws;
  size_t off = 0;
  auto A = [&](size_t bytes) { size_t o = off; off = (off + bytes + 255) & ~(size_t)255; return o; };
  int*    rowptr   = (int*)(w + A((size_t)(N + 1) * 4));
  int*    fill     = (int*)(w + A((size_t)2 * N * 4));
  int*    esort    = (int*)(w + A((size_t)E * 4));
  int*    esrc     = (int*)(w + A((size_t)E * 4));
  float*  eac      = (float*)(w + A((size_t)E * 16 * 4));
  float*  hbuf     = (float*)(w + A((size_t)N * HD * 4));
  float*  xlb      = (float*)(w + A((size_t)N * HD * 4));
  float*  xrb      = (float*)(w + A((size_t)N * HD * 4));
  float*  partials = (float*)(w + A((size_t)GSTAT * 512 * 4));
  float*  bnss     = (float*)(w + A(512 * 4));
  ushort* hhi      = (ushort*)(w + A((size_t)N * HD * 2));
  ushort* hlo      = (ushort*)(w + A((size_t)N * HD * 2));
  ushort* wthi[2], *wtlo[2];
  for (int l = 0; l < 2; ++l) {
    wthi[l] = (ushort*)(w + A(512 * 256 * 2));
    wtlo[l] = (ushort*)(w + A(512 * 256 * 2));
  }

  // CSR by dst; per-node order fixed by csr_finish sort
  hipMemsetAsync(fill, 0, (size_t)2 * N * 4, stream);
  hist_kernel<<<(E + 255) / 256, 256, 0, stream>>>(dstA, fill, E);
  scan_kernel<<<1, 1024, 0, stream>>>(fill, rowptr, N);
  scatter_kernel<<<(E + 255) / 256, 256, 0, stream>>>(dstA, rowptr, fill + N, esort, E);
  csr_finish<<<(N + 3) / 4, 256, 0, stream>>>(srcA, rowptr, esort, ea, esrc, eac, N);
  // weight split+transpose for MFMA layers (independent of h)
  split_w<<<512, 256, 0, stream>>>(Wl[1], Wr[1], wthi[0], wtlo[0]);
  split_w<<<512, 256, 0, stream>>>(Wl[2], Wr[2], wthi[1], wtlo[1]);

  for (int l = 0; l < 3; ++l) {
    if (l == 0) {
      gemm_dual6<<<(N + 31) / 32, 256, 0, stream>>>(x, Wl[0], Wr[0], xlb, xrb, N);
    } else {
      bn_finalize<<<1, 256, 0, stream>>>(partials, gamma[l - 1], beta[l - 1], bnss, (float)N);
      int total4 = N * HD / 4;
      bn_convert<<<(total4 + 255) / 256, 256, 0, stream>>>((const float4*)hbuf, bnss,
                                                           (ushort4*)hhi, (ushort4*)hlo, total4);
      gemm_mfma<<<(N + 15) / 16, 256, 0, stream>>>(hhi, hlo, wthi[l - 1], wtlo[l - 1],
                                                   xlb, xrb, N);
    }
    gat_kernel<<<N, 64, 0, stream>>>(xlb, xrb, esrc, eac, esort, srcA, ea, rowptr,
                                     We[l], att[l], bc[l], hbuf, N);
    bn_stats<<<GSTAT, 256, 0, stream>>>(hbuf, partials, N);
  }

  head_kernel<<<B, 256, 0, stream>>>(hbuf, partials, gamma[2], beta[2], batch, gf,
                                     W1, b1, W2, b2, W3, b3, (float*)d_out, N, (float)N);
}

// Round 15
// 818.585 us; speedup vs baseline: 1.0083x; 1.0083x over previous
//
#include <hip/hip_runtime.h>
#include <math.h>

#define HD 256
#define NEG 0.2f
#define BN_EPS 1e-5f
#define GSTAT 256  // deterministic BN partial blocks
#define APAD 8

typedef __attribute__((ext_vector_type(8))) short short8v;   // 8 bf16 (4 VGPRs)
typedef __attribute__((ext_vector_type(4))) float f32x4;     // MFMA accumulator

__device__ __forceinline__ ushort bf16_rn(float x) {
  unsigned u = __float_as_uint(x);
  return (ushort)((u + 0x7FFFu + ((u >> 16) & 1u)) >> 16);
}
__device__ __forceinline__ float bf16_to_f(ushort b) {
  return __uint_as_float(((unsigned)b) << 16);
}

// ---------------- CSR build (by dst) ----------------
__global__ void hist_kernel(const int* __restrict__ dst, int* __restrict__ cnt, int E) {
  int i = blockIdx.x * blockDim.x + threadIdx.x;
  if (i < E) atomicAdd(&cnt[dst[i]], 1);
}

__global__ __launch_bounds__(1024) void scan_kernel(const int* __restrict__ cnt,
                                                    int* __restrict__ rowptr, int n) {
  __shared__ int sdata[1024];
  int t = threadIdx.x;
  int ipt = (n + 1023) >> 10;
  int base = t * ipt;
  int s = 0;
  for (int i = 0; i < ipt; ++i) { int idx = base + i; if (idx < n) s += cnt[idx]; }
  sdata[t] = s;
  __syncthreads();
  for (int off = 1; off < 1024; off <<= 1) {
    int v = (t >= off) ? sdata[t - off] : 0;
    __syncthreads();
    sdata[t] += v;
    __syncthreads();
  }
  int run = (t == 0) ? 0 : sdata[t - 1];
  for (int i = 0; i < ipt; ++i) {
    int idx = base + i;
    if (idx < n) { run += cnt[idx]; rowptr[idx + 1] = run; }
  }
  if (t == 0) rowptr[0] = 0;
}

__global__ void scatter_kernel(const int* __restrict__ dst, const int* __restrict__ rowptr,
                               int* __restrict__ fill, int* __restrict__ esort, int E) {
  int i = blockIdx.x * blockDim.x + threadIdx.x;
  if (i < E) {
    int d = dst[i];
    int pos = atomicAdd(&fill[d], 1);
    esort[rowptr[d] + pos] = i;
  }
}

// ---------------- per-node sort + CSR-ordered index/edge-attr materialization ----------------
__global__ __launch_bounds__(256) void csr_finish(const int* __restrict__ src,
                                                  const int* __restrict__ rowptr,
                                                  const int* __restrict__ esort,
                                                  const float* __restrict__ ea,
                                                  int* __restrict__ esrc,
                                                  float* __restrict__ eac, int n) {
  int t = threadIdx.x;
  int lane = t & 63;
  int node = __builtin_amdgcn_readfirstlane(blockIdx.x * 4 + (t >> 6));
  if (node >= n) return;
  int pbeg = rowptr[node], pend = rowptr[node + 1];
  int deg = pend - pbeg;
  if (deg == 0 || deg > 64) return;
  int v = (lane < deg) ? esort[pbeg + lane] : 0x7fffffff;
#pragma unroll
  for (int k = 2; k <= 64; k <<= 1) {
#pragma unroll
    for (int j = k >> 1; j >= 1; j >>= 1) {
      int u = __shfl_xor(v, j);
      bool keepmin = (((lane & k) == 0) == ((lane & j) == 0));
      v = keepmin ? (v < u ? v : u) : (v > u ? v : u);
    }
  }
  if (lane < deg) {
    esrc[pbeg + lane] = src[v];
    const float4* s4 = (const float4*)(ea + (size_t)v * 16);
    float4* d4 = (float4*)(eac + (size_t)(pbeg + lane) * 16);
    d4[0] = s4[0]; d4[1] = s4[1]; d4[2] = s4[2]; d4[3] = s4[3];
  }
}

// ---------------- dual GEMM K=6 (layer 0) ----------------
__global__ __launch_bounds__(256) void gemm_dual6(const float* __restrict__ h,
                                                  const float* __restrict__ Wl,
                                                  const float* __restrict__ Wr,
                                                  float* __restrict__ xlo, float* __restrict__ xro,
                                                  int n) {
  __shared__ float hs[32 * 6];
  int r0 = blockIdx.x * 32;
  int t = threadIdx.x;
  int nr = min(32, n - r0);
  int tot = nr * 6;
  for (int i = t; i < tot; i += 256) hs[i] = h[(size_t)r0 * 6 + i];
  __syncthreads();
  float accl[32], accr[32];
#pragma unroll
  for (int r = 0; r < 32; ++r) { accl[r] = 0.f; accr[r] = 0.f; }
  int j = t;
  for (int k = 0; k < 6; ++k) {
    float wl = Wl[k * HD + j];
    float wr = Wr[k * HD + j];
#pragma unroll
    for (int r = 0; r < 32; ++r) {
      float hv = hs[r * 6 + k];
      accl[r] += hv * wl;
      accr[r] += hv * wr;
    }
  }
  for (int r = 0; r < nr; ++r) {
    xlo[(size_t)(r0 + r) * HD + j] = accl[r];
    xro[(size_t)(r0 + r) * HD + j] = accr[r];
  }
}

// ---------------- weight split+transpose (once per layer): Wt[j][k] hi/lo bf16 ----------------
__global__ __launch_bounds__(256) void split_w(const float* __restrict__ Wl,
                                               const float* __restrict__ Wr,
                                               ushort* __restrict__ wthi,
                                               ushort* __restrict__ wtlo) {
  int idx = blockIdx.x * 256 + threadIdx.x;  // 512*256
  int j = idx >> 8;
  int k = idx & 255;
  float v = (j < 256) ? Wl[k * 256 + j] : Wr[k * 256 + (j - 256)];
  ushort hi = bf16_rn(v);
  float lo = v - bf16_to_f(hi);
  wthi[idx] = hi;
  wtlo[idx] = bf16_rn(lo);
}

// ---------------- BN finalize (deterministic, 1 block) ----------------
__global__ void bn_finalize(const float* __restrict__ partials, const float* __restrict__ gamma,
                            const float* __restrict__ beta, float* __restrict__ ss, float nf) {
  int c = threadIdx.x;
  float s = 0.f, s2 = 0.f;
  for (int g = 0; g < GSTAT; ++g) {
    s += partials[g * 512 + c];
    s2 += partials[g * 512 + 256 + c];
  }
  float mean = s / nf;
  float var = s2 / nf - mean * mean;
  float sc = gamma[c] * rsqrtf(var + BN_EPS);
  ss[c] = sc;
  ss[256 + c] = beta[c] - mean * sc;
}

// ---------------- BN+ReLU apply + hi/lo bf16 split (vectorized x4) ----------------
__global__ __launch_bounds__(256) void bn_convert(const float4* __restrict__ h,
                                                  const float* __restrict__ ss,
                                                  ushort4* __restrict__ hhi,
                                                  ushort4* __restrict__ hlo, int total4) {
  int i = blockIdx.x * 256 + threadIdx.x;
  if (i >= total4) return;
  int c = (i & 63) * 4;
  float4 v = h[i];
  float a0 = fmaxf(v.x * ss[c + 0] + ss[256 + c + 0], 0.f);
  float a1 = fmaxf(v.y * ss[c + 1] + ss[256 + c + 1], 0.f);
  float a2 = fmaxf(v.z * ss[c + 2] + ss[256 + c + 2], 0.f);
  float a3 = fmaxf(v.w * ss[c + 3] + ss[256 + c + 3], 0.f);
  ushort4 hi, lo;
  hi.x = bf16_rn(a0); lo.x = bf16_rn(a0 - bf16_to_f(hi.x));
  hi.y = bf16_rn(a1); lo.y = bf16_rn(a1 - bf16_to_f(hi.y));
  hi.z = bf16_rn(a2); lo.z = bf16_rn(a2 - bf16_to_f(hi.z));
  hi.w = bf16_rn(a3); lo.w = bf16_rn(a3 - bf16_to_f(hi.w));
  hhi[i] = hi;
  hlo[i] = lo;
}

// ---------------- MFMA GEMM, full-N tile: block = 16 rows x 512 cols ----------------
__global__ __launch_bounds__(256) void gemm_mfma(const ushort* __restrict__ hhi,
                                                 const ushort* __restrict__ hlo,
                                                 const ushort* __restrict__ wthi,
                                                 const ushort* __restrict__ wtlo,
                                                 float* __restrict__ xlo_,
                                                 float* __restrict__ xro_, int n) {
  __shared__ ushort Ahi[16][256 + APAD];
  __shared__ ushort Alo[16][256 + APAD];
  int t = threadIdx.x;
  int r0 = blockIdx.x * 16;
  if (r0 >= n) return;
  {
    const ushort4* ghi = (const ushort4*)(hhi + (size_t)r0 * 256);
    const ushort4* glo = (const ushort4*)(hlo + (size_t)r0 * 256);
    for (int i = t; i < 1024; i += 256) {
      int row = i >> 6, c4 = (i & 63) * 4;
      ushort4 v = ghi[i];
      *(ushort4*)&Ahi[row][c4] = v;
      ushort4 u = glo[i];
      *(ushort4*)&Alo[row][c4] = u;
    }
  }
  __syncthreads();
  int wid = t >> 6, lane = t & 63;
  int lr = lane & 15, lk = lane >> 4;
  int cbase = wid * 128;
  f32x4 acc[8];
#pragma unroll
  for (int f = 0; f < 8; ++f) acc[f] = (f32x4){0.f, 0.f, 0.f, 0.f};
#pragma unroll
  for (int kk = 0; kk < 8; ++kk) {
    int ko = kk * 32 + lk * 8;
    short8v ahi = *(const short8v*)&Ahi[lr][ko];
    short8v alo = *(const short8v*)&Alo[lr][ko];
#pragma unroll
    for (int f = 0; f < 8; ++f) {
      size_t cc = (size_t)(cbase + f * 16 + lr);
      short8v bhi = *(const short8v*)(wthi + cc * 256 + ko);
      short8v blo = *(const short8v*)(wtlo + cc * 256 + ko);
      acc[f] = __builtin_amdgcn_mfma_f32_16x16x32_bf16(ahi, bhi, acc[f], 0, 0, 0);
      acc[f] = __builtin_amdgcn_mfma_f32_16x16x32_bf16(ahi, blo, acc[f], 0, 0, 0);
      acc[f] = __builtin_amdgcn_mfma_f32_16x16x32_bf16(alo, bhi, acc[f], 0, 0, 0);
    }
  }
#pragma unroll
  for (int f = 0; f < 8; ++f) {
    int cc = cbase + f * 16 + lr;
    float* outp = (cc < 256) ? (xlo_ + cc) : (xro_ + (cc - 256));
#pragma unroll
    for (int j = 0; j < 4; ++j)
      outp[(size_t)(r0 + lk * 4 + j) * 256] = acc[f][j];
  }
}

// ---------------- fused GATv2 layer: two-pass softmax, 1 wave = 1 node ----------------
// Pass A: scores only (independent 4-edge batches; lane-held scores sc0/sc1 per
// 32-lane head-half). Normalize via 6 shuffles. Pass B: pure weighted gather,
// 8-deep, zero serial deps. w4 (We slice, pinned) dies after pass A -> registers
// recycle into pass B's xv[8]. R5 proved this structure numerically (2.4e-4);
// R5's failure was spill at VGPR cap 85 — here cap is 128 (64,4), est ~120.
__global__ __launch_bounds__(64, 4) void gat_kernel(const float* __restrict__ xl,
                                                    const float* __restrict__ xr,
                                                    const int* __restrict__ esrc,
                                                    const float* __restrict__ eac,
                                                    const int* __restrict__ esort,
                                                    const int* __restrict__ src,
                                                    const float* __restrict__ ea,
                                                    const int* __restrict__ rowptr,
                                                    const float* __restrict__ We,
                                                    const float* __restrict__ att,
                                                    const float* __restrict__ bc,
                                                    float* __restrict__ hout, int n) {
  int lane = threadIdx.x;
  int node = blockIdx.x;
  if (node >= n) return;
  int c = lane * 4;
  size_t nb = (size_t)node * HD;
  float4 bc4 = *(const float4*)(bc + c);
  int pbeg = rowptr[node], pend = rowptr[node + 1];
  int deg = pend - pbeg;
  if (deg == 0) { *(float4*)(hout + nb + c) = bc4; return; }

  float4 att4 = *(const float4*)(att + c);
  float4 xr4 = *(const float4*)(xr + nb + c);
  float4 acc = make_float4(0.f, 0.f, 0.f, 0.f);
  int l31 = lane & 31;
  int half = lane & 32;

  if (deg <= 64) {
    int es = (lane < deg) ? esrc[pbeg + lane] : 0;
    float sc0 = -3.0e38f, sc1 = -3.0e38f;
    {
      // ---- pass A: edge scores (w4 live only here) ----
      float4 w4[16];
#pragma unroll
      for (int k = 0; k < 16; ++k) w4[k] = *(const float4*)(We + k * HD + c);
#pragma unroll
      for (int k = 0; k < 16; ++k)
        asm volatile("" : "+v"(w4[k].x), "+v"(w4[k].y), "+v"(w4[k].z), "+v"(w4[k].w));
      for (int b = 0; b < deg; b += 4) {
        int nbt = min(4, deg - b);
        float4 xv[4];
#pragma unroll
        for (int i = 0; i < 4; ++i) {
          if (i < nbt) {
            int si = __builtin_amdgcn_readfirstlane(__shfl(es, b + i));
            xv[i] = *(const float4*)(xl + (size_t)si * HD + c);
          }
        }
#pragma unroll
        for (int i = 0; i < 4; ++i) {
          if (i < nbt) {
            const float* ear = eac + (size_t)(pbeg + b + i) * 16;  // uniform -> s_load
            float4 v;
            v.x = xv[i].x + xr4.x;
            v.y = xv[i].y + xr4.y;
            v.z = xv[i].z + xr4.z;
            v.w = xv[i].w + xr4.w;
#pragma unroll
            for (int k = 0; k < 16; ++k) {
              float av = ear[k];
              v.x += av * w4[k].x;
              v.y += av * w4[k].y;
              v.z += av * w4[k].z;
              v.w += av * w4[k].w;
            }
            float l0 = v.x > 0.f ? v.x : NEG * v.x;
            float l1 = v.y > 0.f ? v.y : NEG * v.y;
            float l2 = v.z > 0.f ? v.z : NEG * v.z;
            float l3 = v.w > 0.f ? v.w : NEG * v.w;
            float pv = l0 * att4.x + l1 * att4.y + l2 * att4.z + l3 * att4.w;
            pv += __shfl_xor(pv, 16);
            pv += __shfl_xor(pv, 8);
            pv += __shfl_xor(pv, 4);
            pv += __shfl_xor(pv, 2);
            pv += __shfl_xor(pv, 1);
            int idx = b + i;  // uniform
            if (idx < 32) sc0 = (l31 == idx) ? pv : sc0;
            else          sc1 = (l31 == idx - 32) ? pv : sc1;
          }
        }
      }
    }
    // ---- softmax normalization (per half/head) ----
    float mm = fmaxf(sc0, sc1);
    mm = fmaxf(mm, __shfl_xor(mm, 16));
    mm = fmaxf(mm, __shfl_xor(mm, 8));
    mm = fmaxf(mm, __shfl_xor(mm, 4));
    mm = fmaxf(mm, __shfl_xor(mm, 2));
    mm = fmaxf(mm, __shfl_xor(mm, 1));
    float p0 = (l31 < deg) ? __expf(sc0 - mm) : 0.f;
    float p1 = (l31 + 32 < deg) ? __expf(sc1 - mm) : 0.f;
    float den = p0 + p1;
    den += __shfl_xor(den, 16);
    den += __shfl_xor(den, 8);
    den += __shfl_xor(den, 4);
    den += __shfl_xor(den, 2);
    den += __shfl_xor(den, 1);
    float inv = 1.f / den;  // deg>=1 -> den>=1
    // ---- pass B: weighted aggregation (independent, 8 gathers in flight) ----
    for (int b = 0; b < deg; b += 8) {
      int nbt = min(8, deg - b);
      float4 xv[8];
#pragma unroll
      for (int i = 0; i < 8; ++i) {
        if (i < nbt) {
          int si = __builtin_amdgcn_readfirstlane(__shfl(es, b + i));
          xv[i] = *(const float4*)(xl + (size_t)si * HD + c);
        }
      }
#pragma unroll
      for (int i = 0; i < 8; ++i) {
        if (i < nbt) {
          int idx = b + i;  // uniform
          float wgt = ((idx < 32) ? __shfl(p0, half + idx) : __shfl(p1, half + idx - 32)) * inv;
          acc.x += wgt * xv[i].x;
          acc.y += wgt * xv[i].y;
          acc.z += wgt * xv[i].z;
          acc.w += wgt * xv[i].w;
        }
      }
    }
  } else {
    // deterministic fallback (deg>64, ~never): ascending-edge-id online softmax
    float4 w4[16];
#pragma unroll
    for (int k = 0; k < 16; ++k) w4[k] = *(const float4*)(We + k * HD + c);
    float m = -3.0e38f, d = 0.f;
    int last = -1;
    for (int r = 0; r < deg; ++r) {
      int mymin = 0x7fffffff;
      for (int p = pbeg + lane; p < pend; p += 64) {
        int v = esort[p];
        mymin = (v > last && v < mymin) ? v : mymin;
      }
#pragma unroll
      for (int off = 32; off >= 1; off >>= 1) {
        int u = __shfl_xor(mymin, off);
        mymin = min(mymin, u);
      }
      int e = __builtin_amdgcn_readfirstlane(mymin);
      last = e;
      int s = __builtin_amdgcn_readfirstlane(src[e]);
      float4 xv = *(const float4*)(xl + (size_t)s * HD + c);
      const float* ear = ea + (size_t)e * 16;
      float4 v;
      v.x = xv.x + xr4.x; v.y = xv.y + xr4.y; v.z = xv.z + xr4.z; v.w = xv.w + xr4.w;
#pragma unroll
      for (int k = 0; k < 16; ++k) {
        float av = ear[k];
        v.x += av * w4[k].x;
        v.y += av * w4[k].y;
        v.z += av * w4[k].z;
        v.w += av * w4[k].w;
      }
      float l0 = v.x > 0.f ? v.x : NEG * v.x;
      float l1 = v.y > 0.f ? v.y : NEG * v.y;
      float l2 = v.z > 0.f ? v.z : NEG * v.z;
      float l3 = v.w > 0.f ? v.w : NEG * v.w;
      float pv = l0 * att4.x + l1 * att4.y + l2 * att4.z + l3 * att4.w;
      pv += __shfl_xor(pv, 16);
      pv += __shfl_xor(pv, 8);
      pv += __shfl_xor(pv, 4);
      pv += __shfl_xor(pv, 2);
      pv += __shfl_xor(pv, 1);
      float rs, pe;
      if (pv > m) { rs = __expf(m - pv); m = pv; pe = 1.f; }
      else        { rs = 1.f; pe = __expf(pv - m); }
      d = d * rs + pe;
      acc.x = acc.x * rs + pe * xv.x;
      acc.y = acc.y * rs + pe * xv.y;
      acc.z = acc.z * rs + pe * xv.z;
      acc.w = acc.w * rs + pe * xv.w;
    }
    float inv2 = d > 0.f ? 1.f / d : 0.f;
    acc.x *= inv2; acc.y *= inv2; acc.z *= inv2; acc.w *= inv2;
  }
  float4 o;
  o.x = acc.x + bc4.x;
  o.y = acc.y + bc4.y;
  o.z = acc.z + bc4.z;
  o.w = acc.w + bc4.w;
  *(float4*)(hout + nb + c) = o;
}

// ---------------- deterministic BN partials ----------------
__global__ __launch_bounds__(256) void bn_stats(const float* __restrict__ h,
                                                float* __restrict__ partials, int n) {
  int c = threadIdx.x;
  int g = blockIdx.x;
  int rows = (n + GSTAT - 1) / GSTAT;
  int r0 = g * rows;
  int r1 = min(n, r0 + rows);
  float s = 0.f, s2 = 0.f;
  for (int r = r0; r < r1; ++r) {
    float v = h[(size_t)r * HD + c];
    s += v;
    s2 += v * v;
  }
  partials[g * 512 + c] = s;
  partials[g * 512 + 256 + c] = s2;
}

// ---------------- fused head: BN+ReLU + mean-pool + 3-layer MLP ----------------
__global__ __launch_bounds__(256) void head_kernel(const float* __restrict__ h,
                                                   const float* __restrict__ partials,
                                                   const float* __restrict__ gamma,
                                                   const float* __restrict__ beta,
                                                   const int* __restrict__ batch,
                                                   const float* __restrict__ gf,
                                                   const float* __restrict__ W1,
                                                   const float* __restrict__ b1,
                                                   const float* __restrict__ W2,
                                                   const float* __restrict__ b2,
                                                   const float* __restrict__ W3,
                                                   const float* __restrict__ b3,
                                                   float* __restrict__ out, int n, float nf) {
  int b = blockIdx.x, t = threadIdx.x;
  float s = 0.f, s2 = 0.f;
  for (int g = 0; g < GSTAT; ++g) {
    s += partials[g * 512 + t];
    s2 += partials[g * 512 + 256 + t];
  }
  float mean = s / nf;
  float var = s2 / nf - mean * mean;
  float sc = gamma[t] * rsqrtf(var + BN_EPS);
  float sh = beta[t] - mean * sc;

  int lo = 0, hi = n;
  while (lo < hi) { int mid = (lo + hi) >> 1; if (batch[mid] < b) lo = mid + 1; else hi = mid; }
  int s0 = lo;
  lo = 0; hi = n;
  while (lo < hi) { int mid = (lo + hi) >> 1; if (batch[mid] < b + 1) lo = mid + 1; else hi = mid; }
  int s1 = lo;

  float acc = 0.f;
  for (int r = s0; r < s1; ++r) acc += fmaxf(h[(size_t)r * HD + t] * sc + sh, 0.f);

  __shared__ float in_s[264];
  __shared__ float z1s[256];
  __shared__ float z2s[128];
  float cnt = (float)(s1 - s0);
  in_s[t] = (s1 > s0) ? acc / cnt : 0.f;
  if (t < 8) in_s[HD + t] = gf[b * 8 + t];
  __syncthreads();
  float z = b1[t];
  for (int k = 0; k < 264; ++k) z += in_s[k] * W1[(size_t)k * 256 + t];
  z1s[t] = fmaxf(z, 0.f);
  __syncthreads();
  if (t < 128) {
    float a2 = b2[t];
    for (int k = 0; k < 256; ++k) a2 += z1s[k] * W2[k * 128 + t];
    z2s[t] = fmaxf(a2, 0.f);
  }
  __syncthreads();
  if (t < 100) {
    float o = b3[t];
    for (int k = 0; k < 128; ++k) o += z2s[k] * W3[k * 100 + t];
    out[b * 100 + t] = o;
  }
}

extern "C" void kernel_launch(void* const* d_in, const int* in_sizes, int n_in,
                              void* d_out, int out_size, void* d_ws, size_t ws_size,
                              hipStream_t stream) {
  (void)n_in; (void)out_size; (void)ws_size;
  const float* x      = (const float*)d_in[0];
  const int*   ei     = (const int*)d_in[1];
  const float* ea     = (const float*)d_in[2];
  const int*   batch  = (const int*)d_in[3];
  const float* gf     = (const float*)d_in[4];
  const int E = in_sizes[1] / 2;
  const int N = in_sizes[3];
  const int B = in_sizes[4] / 8;
  const int* srcA = ei;
  const int* dstA = ei + E;

  const float *Wl[3], *Wr[3], *We[3], *att[3], *bc[3], *gamma[3], *beta[3];
  for (int l = 0; l < 3; ++l) {
    int base = 5 + 7 * l;
    Wl[l]    = (const float*)d_in[base + 0];
    Wr[l]    = (const float*)d_in[base + 1];
    We[l]    = (const float*)d_in[base + 2];
    att[l]   = (const float*)d_in[base + 3];
    bc[l]    = (const float*)d_in[base + 4];
    gamma[l] = (const float*)d_in[base + 5];
    beta[l]  = (const float*)d_in[base + 6];
  }
  const float* W1 = (const float*)d_in[26];
  const float* b1 = (const float*)d_in[27];
  const float* W2 = (const float*)d_in[28];
  const float* b2 = (const float*)d_in[29];
  const float* W3 = (const float*)d_in[30];
  const float* b3 = (const float*)d_in[31];

  char* w = (char*)d_ws;
  size_t off = 0;
  auto A = [&](size_t bytes) { size_t o = off; off = (off + bytes + 255) & ~(size_t)255; return o; };
  int*    rowptr   = (int*)(w + A((size_t)(N + 1) * 4));
  int*    fill     = (int*)(w + A((size_t)2 * N * 4));
  int*    esort    = (int*)(w + A((size_t)E * 4));
  int*    esrc     = (int*)(w + A((size_t)E * 4));
  float*  eac      = (float*)(w + A((size_t)E * 16 * 4));
  float*  hbuf     = (float*)(w + A((size_t)N * HD * 4));
  float*  xlb      = (float*)(w + A((size_t)N * HD * 4));
  float*  xrb      = (float*)(w + A((size_t)N * HD * 4));
  float*  partials = (float*)(w + A((size_t)GSTAT * 512 * 4));
  float*  bnss     = (float*)(w + A(512 * 4));
  ushort* hhi      = (ushort*)(w + A((size_t)N * HD * 2));
  ushort* hlo      = (ushort*)(w + A((size_t)N * HD * 2));
  ushort* wthi[2], *wtlo[2];
  for (int l = 0; l < 2; ++l) {
    wthi[l] = (ushort*)(w + A(512 * 256 * 2));
    wtlo[l] = (ushort*)(w + A(512 * 256 * 2));
  }

  // CSR by dst; per-node order fixed by csr_finish sort
  hipMemsetAsync(fill, 0, (size_t)2 * N * 4, stream);
  hist_kernel<<<(E + 255) / 256, 256, 0, stream>>>(dstA, fill, E);
  scan_kernel<<<1, 1024, 0, stream>>>(fill, rowptr, N);
  scatter_kernel<<<(E + 255) / 256, 256, 0, stream>>>(dstA, rowptr, fill + N, esort, E);
  csr_finish<<<(N + 3) / 4, 256, 0, stream>>>(srcA, rowptr, esort, ea, esrc, eac, N);
  // weight split+transpose for MFMA layers (independent of h)
  split_w<<<512, 256, 0, stream>>>(Wl[1], Wr[1], wthi[0], wtlo[0]);
  split_w<<<512, 256, 0, stream>>>(Wl[2], Wr[2], wthi[1], wtlo[1]);

  for (int l = 0; l < 3; ++l) {
    if (l == 0) {
      gemm_dual6<<<(N + 31) / 32, 256, 0, stream>>>(x, Wl[0], Wr[0], xlb, xrb, N);
    } else {
      bn_finalize<<<1, 256, 0, stream>>>(partials, gamma[l - 1], beta[l - 1], bnss, (float)N);
      int total4 = N * HD / 4;
      bn_convert<<<(total4 + 255) / 256, 256, 0, stream>>>((const float4*)hbuf, bnss,
                                                           (ushort4*)hhi, (ushort4*)hlo, total4);
      gemm_mfma<<<(N + 15) / 16, 256, 0, stream>>>(hhi, hlo, wthi[l - 1], wtlo[l - 1],
                                                   xlb, xrb, N);
    }
    gat_kernel<<<N, 64, 0, stream>>>(xlb, xrb, esrc, eac, esort, srcA, ea, rowptr,
                                     We[l], att[l], bc[l], hbuf, N);
    bn_stats<<<GSTAT, 256, 0, stream>>>(hbuf, partials, N);
  }

  head_kernel<<<B, 256, 0, stream>>>(hbuf, partials, gamma[2], beta[2], batch, gf,
                                     W1, b1, W2, b2, W3, b3, (float*)d_out, N, (float)N);
}

// Round 16
// 800.936 us; speedup vs baseline: 1.0305x; 1.0220x over previous
//
#include <hip/hip_runtime.h>
#include <math.h>

#define HD 256
#define NEG 0.2f
#define BN_EPS 1e-5f
#define GSTAT 256  // deterministic BN partial blocks
#define APAD 8

typedef __attribute__((ext_vector_type(8))) short short8v;   // 8 bf16 (4 VGPRs)
typedef __attribute__((ext_vector_type(4))) float f32x4;     // MFMA accumulator

__device__ __forceinline__ ushort bf16_rn(float x) {
  unsigned u = __float_as_uint(x);
  return (ushort)((u + 0x7FFFu + ((u >> 16) & 1u)) >> 16);
}
__device__ __forceinline__ float bf16_to_f(ushort b) {
  return __uint_as_float(((unsigned)b) << 16);
}

// ---------------- CSR build (by dst) ----------------
__global__ void hist_kernel(const int* __restrict__ dst, int* __restrict__ cnt, int E) {
  int i = blockIdx.x * blockDim.x + threadIdx.x;
  if (i < E) atomicAdd(&cnt[dst[i]], 1);
}

__global__ __launch_bounds__(1024) void scan_kernel(const int* __restrict__ cnt,
                                                    int* __restrict__ rowptr, int n) {
  __shared__ int sdata[1024];
  int t = threadIdx.x;
  int ipt = (n + 1023) >> 10;
  int base = t * ipt;
  int s = 0;
  for (int i = 0; i < ipt; ++i) { int idx = base + i; if (idx < n) s += cnt[idx]; }
  sdata[t] = s;
  __syncthreads();
  for (int off = 1; off < 1024; off <<= 1) {
    int v = (t >= off) ? sdata[t - off] : 0;
    __syncthreads();
    sdata[t] += v;
    __syncthreads();
  }
  int run = (t == 0) ? 0 : sdata[t - 1];
  for (int i = 0; i < ipt; ++i) {
    int idx = base + i;
    if (idx < n) { run += cnt[idx]; rowptr[idx + 1] = run; }
  }
  if (t == 0) rowptr[0] = 0;
}

__global__ void scatter_kernel(const int* __restrict__ dst, const int* __restrict__ rowptr,
                               int* __restrict__ fill, int* __restrict__ esort, int E) {
  int i = blockIdx.x * blockDim.x + threadIdx.x;
  if (i < E) {
    int d = dst[i];
    int pos = atomicAdd(&fill[d], 1);
    esort[rowptr[d] + pos] = i;
  }
}

// ---------------- per-node sort + CSR-ordered index/edge-attr materialization ----------------
__global__ __launch_bounds__(256) void csr_finish(const int* __restrict__ src,
                                                  const int* __restrict__ rowptr,
                                                  const int* __restrict__ esort,
                                                  const float* __restrict__ ea,
                                                  int* __restrict__ esrc,
                                                  float* __restrict__ eac, int n) {
  int t = threadIdx.x;
  int lane = t & 63;
  int node = __builtin_amdgcn_readfirstlane(blockIdx.x * 4 + (t >> 6));
  if (node >= n) return;
  int pbeg = rowptr[node], pend = rowptr[node + 1];
  int deg = pend - pbeg;
  if (deg == 0 || deg > 64) return;
  int v = (lane < deg) ? esort[pbeg + lane] : 0x7fffffff;
#pragma unroll
  for (int k = 2; k <= 64; k <<= 1) {
#pragma unroll
    for (int j = k >> 1; j >= 1; j >>= 1) {
      int u = __shfl_xor(v, j);
      bool keepmin = (((lane & k) == 0) == ((lane & j) == 0));
      v = keepmin ? (v < u ? v : u) : (v > u ? v : u);
    }
  }
  if (lane < deg) {
    esrc[pbeg + lane] = src[v];
    const float4* s4 = (const float4*)(ea + (size_t)v * 16);
    float4* d4 = (float4*)(eac + (size_t)(pbeg + lane) * 16);
    d4[0] = s4[0]; d4[1] = s4[1]; d4[2] = s4[2]; d4[3] = s4[3];
  }
}

// ---------------- dual GEMM K=6 (layer 0) ----------------
__global__ __launch_bounds__(256) void gemm_dual6(const float* __restrict__ h,
                                                  const float* __restrict__ Wl,
                                                  const float* __restrict__ Wr,
                                                  float* __restrict__ xlo, float* __restrict__ xro,
                                                  int n) {
  __shared__ float hs[32 * 6];
  int r0 = blockIdx.x * 32;
  int t = threadIdx.x;
  int nr = min(32, n - r0);
  int tot = nr * 6;
  for (int i = t; i < tot; i += 256) hs[i] = h[(size_t)r0 * 6 + i];
  __syncthreads();
  float accl[32], accr[32];
#pragma unroll
  for (int r = 0; r < 32; ++r) { accl[r] = 0.f; accr[r] = 0.f; }
  int j = t;
  for (int k = 0; k < 6; ++k) {
    float wl = Wl[k * HD + j];
    float wr = Wr[k * HD + j];
#pragma unroll
    for (int r = 0; r < 32; ++r) {
      float hv = hs[r * 6 + k];
      accl[r] += hv * wl;
      accr[r] += hv * wr;
    }
  }
  for (int r = 0; r < nr; ++r) {
    xlo[(size_t)(r0 + r) * HD + j] = accl[r];
    xro[(size_t)(r0 + r) * HD + j] = accr[r];
  }
}

// ---------------- weight split+transpose (once per layer): Wt[j][k] hi/lo bf16 ----------------
__global__ __launch_bounds__(256) void split_w(const float* __restrict__ Wl,
                                               const float* __restrict__ Wr,
                                               ushort* __restrict__ wthi,
                                               ushort* __restrict__ wtlo) {
  int idx = blockIdx.x * 256 + threadIdx.x;  // 512*256
  int j = idx >> 8;
  int k = idx & 255;
  float v = (j < 256) ? Wl[k * 256 + j] : Wr[k * 256 + (j - 256)];
  ushort hi = bf16_rn(v);
  float lo = v - bf16_to_f(hi);
  wthi[idx] = hi;
  wtlo[idx] = bf16_rn(lo);
}

// ---------------- BN finalize (deterministic, 1 block) ----------------
__global__ void bn_finalize(const float* __restrict__ partials, const float* __restrict__ gamma,
                            const float* __restrict__ beta, float* __restrict__ ss, float nf) {
  int c = threadIdx.x;
  float s = 0.f, s2 = 0.f;
  for (int g = 0; g < GSTAT; ++g) {
    s += partials[g * 512 + c];
    s2 += partials[g * 512 + 256 + c];
  }
  float mean = s / nf;
  float var = s2 / nf - mean * mean;
  float sc = gamma[c] * rsqrtf(var + BN_EPS);
  ss[c] = sc;
  ss[256 + c] = beta[c] - mean * sc;
}

// ---------------- MFMA GEMM, full-N tile, fused BN+ReLU+split on A staging ----------------
// Block = 16 rows x 512 cols. A staged from RAW hbuf: BN (ss) + ReLU + hi/lo bf16 split
// applied during the coalesced LDS fill (was a separate bn_convert dispatch + 20 MB/layer
// hhi/hlo round trip). B (512 KB) L2-resident across all 1250 blocks.
__global__ __launch_bounds__(256) void gemm_mfma(const float* __restrict__ h,
                                                 const float* __restrict__ ss,
                                                 const ushort* __restrict__ wthi,
                                                 const ushort* __restrict__ wtlo,
                                                 float* __restrict__ xlo_,
                                                 float* __restrict__ xro_, int n) {
  __shared__ ushort Ahi[16][256 + APAD];
  __shared__ ushort Alo[16][256 + APAD];
  int t = threadIdx.x;
  int r0 = blockIdx.x * 16;
  if (r0 >= n) return;
  {
    const float4* gsrc = (const float4*)(h + (size_t)r0 * 256);
    for (int i = t; i < 1024; i += 256) {
      int row = i >> 6, c4 = (i & 63) * 4;
      float4 v = gsrc[i];
      float a0 = fmaxf(v.x * ss[c4 + 0] + ss[256 + c4 + 0], 0.f);
      float a1 = fmaxf(v.y * ss[c4 + 1] + ss[256 + c4 + 1], 0.f);
      float a2 = fmaxf(v.z * ss[c4 + 2] + ss[256 + c4 + 2], 0.f);
      float a3 = fmaxf(v.w * ss[c4 + 3] + ss[256 + c4 + 3], 0.f);
      ushort4 hi, lo;
      hi.x = bf16_rn(a0); lo.x = bf16_rn(a0 - bf16_to_f(hi.x));
      hi.y = bf16_rn(a1); lo.y = bf16_rn(a1 - bf16_to_f(hi.y));
      hi.z = bf16_rn(a2); lo.z = bf16_rn(a2 - bf16_to_f(hi.z));
      hi.w = bf16_rn(a3); lo.w = bf16_rn(a3 - bf16_to_f(hi.w));
      *(ushort4*)&Ahi[row][c4] = hi;
      *(ushort4*)&Alo[row][c4] = lo;
    }
  }
  __syncthreads();
  int wid = t >> 6, lane = t & 63;
  int lr = lane & 15, lk = lane >> 4;
  int cbase = wid * 128;
  f32x4 acc[8];
#pragma unroll
  for (int f = 0; f < 8; ++f) acc[f] = (f32x4){0.f, 0.f, 0.f, 0.f};
#pragma unroll
  for (int kk = 0; kk < 8; ++kk) {
    int ko = kk * 32 + lk * 8;
    short8v ahi = *(const short8v*)&Ahi[lr][ko];
    short8v alo = *(const short8v*)&Alo[lr][ko];
#pragma unroll
    for (int f = 0; f < 8; ++f) {
      size_t cc = (size_t)(cbase + f * 16 + lr);
      short8v bhi = *(const short8v*)(wthi + cc * 256 + ko);
      short8v blo = *(const short8v*)(wtlo + cc * 256 + ko);
      acc[f] = __builtin_amdgcn_mfma_f32_16x16x32_bf16(ahi, bhi, acc[f], 0, 0, 0);
      acc[f] = __builtin_amdgcn_mfma_f32_16x16x32_bf16(ahi, blo, acc[f], 0, 0, 0);
      acc[f] = __builtin_amdgcn_mfma_f32_16x16x32_bf16(alo, bhi, acc[f], 0, 0, 0);
    }
  }
#pragma unroll
  for (int f = 0; f < 8; ++f) {
    int cc = cbase + f * 16 + lr;
    float* outp = (cc < 256) ? (xlo_ + cc) : (xro_ + (cc - 256));
#pragma unroll
    for (int j = 0; j < 4; ++j)
      outp[(size_t)(r0 + lk * 4 + j) * 256] = acc[f][j];
  }
}

// ---------------- fused GATv2 layer: 1 wave = 1 node, We pinned in VGPRs ----------------
// R13 configuration (empirical optimum: 117 µs): batch-4 online softmax; R14 batch-8
// (+VALU overhead) and R15 two-pass (+107 MB gather traffic) both regressed.
__global__ __launch_bounds__(64, 4) void gat_kernel(const float* __restrict__ xl,
                                                    const float* __restrict__ xr,
                                                    const int* __restrict__ esrc,
                                                    const float* __restrict__ eac,
                                                    const int* __restrict__ esort,
                                                    const int* __restrict__ src,
                                                    const float* __restrict__ ea,
                                                    const int* __restrict__ rowptr,
                                                    const float* __restrict__ We,
                                                    const float* __restrict__ att,
                                                    const float* __restrict__ bc,
                                                    float* __restrict__ hout, int n) {
  int lane = threadIdx.x;
  int node = blockIdx.x;
  if (node >= n) return;
  int c = lane * 4;
  size_t nb = (size_t)node * HD;
  float4 bc4 = *(const float4*)(bc + c);
  int pbeg = rowptr[node], pend = rowptr[node + 1];
  int deg = pend - pbeg;
  if (deg == 0) { *(float4*)(hout + nb + c) = bc4; return; }

  float4 w4[16];
#pragma unroll
  for (int k = 0; k < 16; ++k) w4[k] = *(const float4*)(We + k * HD + c);
  // pin We slice in VGPRs: opaque to the compiler -> cannot rematerialize/reload
#pragma unroll
  for (int k = 0; k < 16; ++k)
    asm volatile("" : "+v"(w4[k].x), "+v"(w4[k].y), "+v"(w4[k].z), "+v"(w4[k].w));

  float4 att4 = *(const float4*)(att + c);
  float4 xr4 = *(const float4*)(xr + nb + c);
  float4 acc = make_float4(0.f, 0.f, 0.f, 0.f);
  float m = -3.0e38f, d = 0.f;

  if (deg <= 64) {
    int es = (lane < deg) ? esrc[pbeg + lane] : 0;
    for (int b = 0; b < deg; b += 4) {
      int nbt = min(4, deg - b);
      float4 xv[4];
#pragma unroll
      for (int i = 0; i < 4; ++i) {
        if (i < nbt) {
          int si = __builtin_amdgcn_readfirstlane(__shfl(es, b + i));
          xv[i] = *(const float4*)(xl + (size_t)si * HD + c);
        }
      }
#pragma unroll
      for (int i = 0; i < 4; ++i) {
        if (i < nbt) {
          const float* ear = eac + (size_t)(pbeg + b + i) * 16;  // uniform -> s_load
          float4 v;
          v.x = xv[i].x + xr4.x;
          v.y = xv[i].y + xr4.y;
          v.z = xv[i].z + xr4.z;
          v.w = xv[i].w + xr4.w;
#pragma unroll
          for (int k = 0; k < 16; ++k) {
            float av = ear[k];
            v.x += av * w4[k].x;
            v.y += av * w4[k].y;
            v.z += av * w4[k].z;
            v.w += av * w4[k].w;
          }
          // leaky_relu(x) = max(x, NEG*x) for 0<NEG<1
          float l0 = fmaxf(v.x, NEG * v.x);
          float l1 = fmaxf(v.y, NEG * v.y);
          float l2 = fmaxf(v.z, NEG * v.z);
          float l3 = fmaxf(v.w, NEG * v.w);
          float pv = l0 * att4.x + l1 * att4.y + l2 * att4.z + l3 * att4.w;
          pv += __shfl_xor(pv, 16);
          pv += __shfl_xor(pv, 8);
          pv += __shfl_xor(pv, 4);
          pv += __shfl_xor(pv, 2);
          pv += __shfl_xor(pv, 1);
          float rs, pe;
          if (pv > m) { rs = __expf(m - pv); m = pv; pe = 1.f; }
          else        { rs = 1.f; pe = __expf(pv - m); }
          d = d * rs + pe;
          acc.x = acc.x * rs + pe * xv[i].x;
          acc.y = acc.y * rs + pe * xv[i].y;
          acc.z = acc.z * rs + pe * xv[i].z;
          acc.w = acc.w * rs + pe * xv[i].w;
        }
      }
    }
  } else {
    // deterministic fallback (deg>64, ~never): ascending-edge-id online softmax
    int last = -1;
    for (int r = 0; r < deg; ++r) {
      int mymin = 0x7fffffff;
      for (int p = pbeg + lane; p < pend; p += 64) {
        int v = esort[p];
        mymin = (v > last && v < mymin) ? v : mymin;
      }
#pragma unroll
      for (int off = 32; off >= 1; off >>= 1) {
        int u = __shfl_xor(mymin, off);
        mymin = min(mymin, u);
      }
      int e = __builtin_amdgcn_readfirstlane(mymin);
      last = e;
      int s = __builtin_amdgcn_readfirstlane(src[e]);
      float4 xv = *(const float4*)(xl + (size_t)s * HD + c);
      const float* ear = ea + (size_t)e * 16;
      float4 v;
      v.x = xv.x + xr4.x; v.y = xv.y + xr4.y; v.z = xv.z + xr4.z; v.w = xv.w + xr4.w;
#pragma unroll
      for (int k = 0; k < 16; ++k) {
        float av = ear[k];
        v.x += av * w4[k].x;
        v.y += av * w4[k].y;
        v.z += av * w4[k].z;
        v.w += av * w4[k].w;
      }
      float l0 = fmaxf(v.x, NEG * v.x);
      float l1 = fmaxf(v.y, NEG * v.y);
      float l2 = fmaxf(v.z, NEG * v.z);
      float l3 = fmaxf(v.w, NEG * v.w);
      float pv = l0 * att4.x + l1 * att4.y + l2 * att4.z + l3 * att4.w;
      pv += __shfl_xor(pv, 16);
      pv += __shfl_xor(pv, 8);
      pv += __shfl_xor(pv, 4);
      pv += __shfl_xor(pv, 2);
      pv += __shfl_xor(pv, 1);
      float rs, pe;
      if (pv > m) { rs = __expf(m - pv); m = pv; pe = 1.f; }
      else        { rs = 1.f; pe = __expf(pv - m); }
      d = d * rs + pe;
      acc.x = acc.x * rs + pe * xv.x;
      acc.y = acc.y * rs + pe * xv.y;
      acc.z = acc.z * rs + pe * xv.z;
      acc.w = acc.w * rs + pe * xv.w;
    }
  }
  float inv = d > 0.f ? 1.f / d : 0.f;
  float4 o;
  o.x = acc.x * inv + bc4.x;
  o.y = acc.y * inv + bc4.y;
  o.z = acc.z * inv + bc4.z;
  o.w = acc.w * inv + bc4.w;
  *(float4*)(hout + nb + c) = o;
}

// ---------------- deterministic BN partials ----------------
__global__ __launch_bounds__(256) void bn_stats(const float* __restrict__ h,
                                                float* __restrict__ partials, int n) {
  int c = threadIdx.x;
  int g = blockIdx.x;
  int rows = (n + GSTAT - 1) / GSTAT;
  int r0 = g * rows;
  int r1 = min(n, r0 + rows);
  float s = 0.f, s2 = 0.f;
  for (int r = r0; r < r1; ++r) {
    float v = h[(size_t)r * HD + c];
    s += v;
    s2 += v * v;
  }
  partials[g * 512 + c] = s;
  partials[g * 512 + 256 + c] = s2;
}

// ---------------- fused head: BN+ReLU + mean-pool + 3-layer MLP ----------------
__global__ __launch_bounds__(256) void head_kernel(const float* __restrict__ h,
                                                   const float* __restrict__ partials,
                                                   const float* __restrict__ gamma,
                                                   const float* __restrict__ beta,
                                                   const int* __restrict__ batch,
                                                   const float* __restrict__ gf,
                                                   const float* __restrict__ W1,
                                                   const float* __restrict__ b1,
                                                   const float* __restrict__ W2,
                                                   const float* __restrict__ b2,
                                                   const float* __restrict__ W3,
                                                   const float* __restrict__ b3,
                                                   float* __restrict__ out, int n, float nf) {
  int b = blockIdx.x, t = threadIdx.x;
  float s = 0.f, s2 = 0.f;
  for (int g = 0; g < GSTAT; ++g) {
    s += partials[g * 512 + t];
    s2 += partials[g * 512 + 256 + t];
  }
  float mean = s / nf;
  float var = s2 / nf - mean * mean;
  float sc = gamma[t] * rsqrtf(var + BN_EPS);
  float sh = beta[t] - mean * sc;

  int lo = 0, hi = n;
  while (lo < hi) { int mid = (lo + hi) >> 1; if (batch[mid] < b) lo = mid + 1; else hi = mid; }
  int s0 = lo;
  lo = 0; hi = n;
  while (lo < hi) { int mid = (lo + hi) >> 1; if (batch[mid] < b + 1) lo = mid + 1; else hi = mid; }
  int s1 = lo;

  float acc = 0.f;
  for (int r = s0; r < s1; ++r) acc += fmaxf(h[(size_t)r * HD + t] * sc + sh, 0.f);

  __shared__ float in_s[264];
  __shared__ float z1s[256];
  __shared__ float z2s[128];
  float cnt = (float)(s1 - s0);
  in_s[t] = (s1 > s0) ? acc / cnt : 0.f;
  if (t < 8) in_s[HD + t] = gf[b * 8 + t];
  __syncthreads();
  float z = b1[t];
  for (int k = 0; k < 264; ++k) z += in_s[k] * W1[(size_t)k * 256 + t];
  z1s[t] = fmaxf(z, 0.f);
  __syncthreads();
  if (t < 128) {
    float a2 = b2[t];
    for (int k = 0; k < 256; ++k) a2 += z1s[k] * W2[k * 128 + t];
    z2s[t] = fmaxf(a2, 0.f);
  }
  __syncthreads();
  if (t < 100) {
    float o = b3[t];
    for (int k = 0; k < 128; ++k) o += z2s[k] * W3[k * 100 + t];
    out[b * 100 + t] = o;
  }
}

extern "C" void kernel_launch(void* const* d_in, const int* in_sizes, int n_in,
                              void* d_out, int out_size, void* d_ws, size_t ws_size,
                              hipStream_t stream) {
  (void)n_in; (void)out_size; (void)ws_size;
  const float* x      = (const float*)d_in[0];
  const int*   ei     = (const int*)d_in[1];
  const float* ea     = (const float*)d_in[2];
  const int*   batch  = (const int*)d_in[3];
  const float* gf     = (const float*)d_in[4];
  const int E = in_sizes[1] / 2;
  const int N = in_sizes[3];
  const int B = in_sizes[4] / 8;
  const int* srcA = ei;
  const int* dstA = ei + E;

  const float *Wl[3], *Wr[3], *We[3], *att[3], *bc[3], *gamma[3], *beta[3];
  for (int l = 0; l < 3; ++l) {
    int base = 5 + 7 * l;
    Wl[l]    = (const float*)d_in[base + 0];
    Wr[l]    = (const float*)d_in[base + 1];
    We[l]    = (const float*)d_in[base + 2];
    att[l]   = (const float*)d_in[base + 3];
    bc[l]    = (const float*)d_in[base + 4];
    gamma[l] = (const float*)d_in[base + 5];
    beta[l]  = (const float*)d_in[base + 6];
  }
  const float* W1 = (const float*)d_in[26];
  const float* b1 = (const float*)d_in[27];
  const float* W2 = (const float*)d_in[28];
  const float* b2 = (const float*)d_in[29];
  const float* W3 = (const float*)d_in[30];
  const float* b3 = (const float*)d_in[31];

  char* w = (char*)d_ws;
  size_t off = 0;
  auto A = [&](size_t bytes) { size_t o = off; off = (off + bytes + 255) & ~(size_t)255; return o; };
  int*    rowptr   = (int*)(w + A((size_t)(N + 1) * 4));
  int*    fill     = (int*)(w + A((size_t)2 * N * 4));
  int*    esort    = (int*)(w + A((size_t)E * 4));
  int*    esrc     = (int*)(w + A((size_t)E * 4));
  float*  eac      = (float*)(w + A((size_t)E * 16 * 4));
  float*  hbuf     = (float*)(w + A((size_t)N * HD * 4));
  float*  xlb      = (float*)(w + A((size_t)N * HD * 4));
  float*  xrb      = (float*)(w + A((size_t)N * HD * 4));
  float*  partials = (float*)(w + A((size_t)GSTAT * 512 * 4));
  float*  bnss     = (float*)(w + A(512 * 4));
  ushort* wthi[2], *wtlo[2];
  for (int l = 0; l < 2; ++l) {
    wthi[l] = (ushort*)(w + A(512 * 256 * 2));
    wtlo[l] = (ushort*)(w + A(512 * 256 * 2));
  }

  // CSR by dst; per-node order fixed by csr_finish sort
  hipMemsetAsync(fill, 0, (size_t)2 * N * 4, stream);
  hist_kernel<<<(E + 255) / 256, 256, 0, stream>>>(dstA, fill, E);
  scan_kernel<<<1, 1024, 0, stream>>>(fill, rowptr, N);
  scatter_kernel<<<(E + 255) / 256, 256, 0, stream>>>(dstA, rowptr, fill + N, esort, E);
  csr_finish<<<(N + 3) / 4, 256, 0, stream>>>(srcA, rowptr, esort, ea, esrc, eac, N);
  // weight split+transpose for MFMA layers (independent of h)
  split_w<<<512, 256, 0, stream>>>(Wl[1], Wr[1], wthi[0], wtlo[0]);
  split_w<<<512, 256, 0, stream>>>(Wl[2], Wr[2], wthi[1], wtlo[1]);

  for (int l = 0; l < 3; ++l) {
    if (l == 0) {
      gemm_dual6<<<(N + 31) / 32, 256, 0, stream>>>(x, Wl[0], Wr[0], xlb, xrb, N);
    } else {
      bn_finalize<<<1, 256, 0, stream>>>(partials, gamma[l - 1], beta[l - 1], bnss, (float)N);
      gemm_mfma<<<(N + 15) / 16, 256, 0, stream>>>(hbuf, bnss, wthi[l - 1], wtlo[l - 1],
                                                   xlb, xrb, N);
    }
    gat_kernel<<<N, 64, 0, stream>>>(xlb, xrb, esrc, eac, esort, srcA, ea, rowptr,
                                     We[l], att[l], bc[l], hbuf, N);
    bn_stats<<<GSTAT, 256, 0, stream>>>(hbuf, partials, N);
  }

  head_kernel<<<B, 256, 0, stream>>>(hbuf, partials, gamma[2], beta[2], batch, gf,
                                     W1, b1, W2, b2, W3, b3, (float*)d_out, N, (float)N);
}

// Round 18
// 767.022 us; speedup vs baseline: 1.0760x; 1.0442x over previous
//
#include <hip/hip_runtime.h>
#include <math.h>

#define HD 256
#define NEG 0.2f
#define BN_EPS 1e-5f
#define GSTAT 256  // deterministic BN partial blocks
#define APAD 8

typedef __attribute__((ext_vector_type(8))) short short8v;   // 8 bf16 (4 VGPRs)
typedef __attribute__((ext_vector_type(4))) float f32x4;     // MFMA accumulator

__device__ __forceinline__ ushort bf16_rn(float x) {
  unsigned u = __float_as_uint(x);
  return (ushort)((u + 0x7FFFu + ((u >> 16) & 1u)) >> 16);
}
__device__ __forceinline__ float bf16_to_f(ushort b) {
  return __uint_as_float(((unsigned)b) << 16);
}

// ---------------- CSR build (by dst) ----------------
__global__ void hist_kernel(const int* __restrict__ dst, int* __restrict__ cnt, int E) {
  int i = blockIdx.x * blockDim.x + threadIdx.x;
  if (i < E) atomicAdd(&cnt[dst[i]], 1);
}

__global__ __launch_bounds__(1024) void scan_kernel(const int* __restrict__ cnt,
                                                    int* __restrict__ rowptr, int n) {
  __shared__ int sdata[1024];
  int t = threadIdx.x;
  int ipt = (n + 1023) >> 10;
  int base = t * ipt;
  int s = 0;
  for (int i = 0; i < ipt; ++i) { int idx = base + i; if (idx < n) s += cnt[idx]; }
  sdata[t] = s;
  __syncthreads();
  for (int off = 1; off < 1024; off <<= 1) {
    int v = (t >= off) ? sdata[t - off] : 0;
    __syncthreads();
    sdata[t] += v;
    __syncthreads();
  }
  int run = (t == 0) ? 0 : sdata[t - 1];
  for (int i = 0; i < ipt; ++i) {
    int idx = base + i;
    if (idx < n) { run += cnt[idx]; rowptr[idx + 1] = run; }
  }
  if (t == 0) rowptr[0] = 0;
}

__global__ void scatter_kernel(const int* __restrict__ dst, const int* __restrict__ rowptr,
                               int* __restrict__ fill, int* __restrict__ esort, int E) {
  int i = blockIdx.x * blockDim.x + threadIdx.x;
  if (i < E) {
    int d = dst[i];
    int pos = atomicAdd(&fill[d], 1);
    esort[rowptr[d] + pos] = i;
  }
}

// ---------------- per-node sort + CSR-ordered index/edge-attr materialization ----------------
__global__ __launch_bounds__(256) void csr_finish(const int* __restrict__ src,
                                                  const int* __restrict__ rowptr,
                                                  const int* __restrict__ esort,
                                                  const float* __restrict__ ea,
                                                  int* __restrict__ esrc,
                                                  float* __restrict__ eac, int n) {
  int t = threadIdx.x;
  int lane = t & 63;
  int node = __builtin_amdgcn_readfirstlane(blockIdx.x * 4 + (t >> 6));
  if (node >= n) return;
  int pbeg = rowptr[node], pend = rowptr[node + 1];
  int deg = pend - pbeg;
  if (deg == 0 || deg > 64) return;
  int v = (lane < deg) ? esort[pbeg + lane] : 0x7fffffff;
#pragma unroll
  for (int k = 2; k <= 64; k <<= 1) {
#pragma unroll
    for (int j = k >> 1; j >= 1; j >>= 1) {
      int u = __shfl_xor(v, j);
      bool keepmin = (((lane & k) == 0) == ((lane & j) == 0));
      v = keepmin ? (v < u ? v : u) : (v > u ? v : u);
    }
  }
  if (lane < deg) {
    esrc[pbeg + lane] = src[v];
    const float4* s4 = (const float4*)(ea + (size_t)v * 16);
    float4* d4 = (float4*)(eac + (size_t)(pbeg + lane) * 16);
    d4[0] = s4[0]; d4[1] = s4[1]; d4[2] = s4[2]; d4[3] = s4[3];
  }
}

// ---------------- dual GEMM K=6 (layer 0) ----------------
__global__ __launch_bounds__(256) void gemm_dual6(const float* __restrict__ h,
                                                  const float* __restrict__ Wl,
                                                  const float* __restrict__ Wr,
                                                  float* __restrict__ xlo, float* __restrict__ xro,
                                                  int n) {
  __shared__ float hs[32 * 6];
  int r0 = blockIdx.x * 32;
  int t = threadIdx.x;
  int nr = min(32, n - r0);
  int tot = nr * 6;
  for (int i = t; i < tot; i += 256) hs[i] = h[(size_t)r0 * 6 + i];
  __syncthreads();
  float accl[32], accr[32];
#pragma unroll
  for (int r = 0; r < 32; ++r) { accl[r] = 0.f; accr[r] = 0.f; }
  int j = t;
  for (int k = 0; k < 6; ++k) {
    float wl = Wl[k * HD + j];
    float wr = Wr[k * HD + j];
#pragma unroll
    for (int r = 0; r < 32; ++r) {
      float hv = hs[r * 6 + k];
      accl[r] += hv * wl;
      accr[r] += hv * wr;
    }
  }
  for (int r = 0; r < nr; ++r) {
    xlo[(size_t)(r0 + r) * HD + j] = accl[r];
    xro[(size_t)(r0 + r) * HD + j] = accr[r];
  }
}

// ---------------- weight split+transpose (once per layer): Wt[j][k] hi/lo bf16 ----------------
__global__ __launch_bounds__(256) void split_w(const float* __restrict__ Wl,
                                               const float* __restrict__ Wr,
                                               ushort* __restrict__ wthi,
                                               ushort* __restrict__ wtlo) {
  int idx = blockIdx.x * 256 + threadIdx.x;  // 512*256
  int j = idx >> 8;
  int k = idx & 255;
  float v = (j < 256) ? Wl[k * 256 + j] : Wr[k * 256 + (j - 256)];
  ushort hi = bf16_rn(v);
  float lo = v - bf16_to_f(hi);
  wthi[idx] = hi;
  wtlo[idx] = bf16_rn(lo);
}

// ---------------- BN finalize (deterministic, 1 block) ----------------
__global__ void bn_finalize(const float* __restrict__ partials, const float* __restrict__ gamma,
                            const float* __restrict__ beta, float* __restrict__ ss, float nf) {
  int c = threadIdx.x;
  float s = 0.f, s2 = 0.f;
  for (int g = 0; g < GSTAT; ++g) {
    s += partials[g * 512 + c];
    s2 += partials[g * 512 + 256 + c];
  }
  float mean = s / nf;
  float var = s2 / nf - mean * mean;
  float sc = gamma[c] * rsqrtf(var + BN_EPS);
  ss[c] = sc;
  ss[256 + c] = beta[c] - mean * sc;
}

// ---------------- MFMA GEMM, full-N tile, fused BN+ReLU+split on A staging ----------------
__global__ __launch_bounds__(256) void gemm_mfma(const float* __restrict__ h,
                                                 const float* __restrict__ ss,
                                                 const ushort* __restrict__ wthi,
                                                 const ushort* __restrict__ wtlo,
                                                 float* __restrict__ xlo_,
                                                 float* __restrict__ xro_, int n) {
  __shared__ ushort Ahi[16][256 + APAD];
  __shared__ ushort Alo[16][256 + APAD];
  int t = threadIdx.x;
  int r0 = blockIdx.x * 16;
  if (r0 >= n) return;
  {
    const float4* gsrc = (const float4*)(h + (size_t)r0 * 256);
    for (int i = t; i < 1024; i += 256) {
      int row = i >> 6, c4 = (i & 63) * 4;
      float4 v = gsrc[i];
      float a0 = fmaxf(v.x * ss[c4 + 0] + ss[256 + c4 + 0], 0.f);
      float a1 = fmaxf(v.y * ss[c4 + 1] + ss[256 + c4 + 1], 0.f);
      float a2 = fmaxf(v.z * ss[c4 + 2] + ss[256 + c4 + 2], 0.f);
      float a3 = fmaxf(v.w * ss[c4 + 3] + ss[256 + c4 + 3], 0.f);
      ushort4 hi, lo;
      hi.x = bf16_rn(a0); lo.x = bf16_rn(a0 - bf16_to_f(hi.x));
      hi.y = bf16_rn(a1); lo.y = bf16_rn(a1 - bf16_to_f(hi.y));
      hi.z = bf16_rn(a2); lo.z = bf16_rn(a2 - bf16_to_f(hi.z));
      hi.w = bf16_rn(a3); lo.w = bf16_rn(a3 - bf16_to_f(hi.w));
      *(ushort4*)&Ahi[row][c4] = hi;
      *(ushort4*)&Alo[row][c4] = lo;
    }
  }
  __syncthreads();
  int wid = t >> 6, lane = t & 63;
  int lr = lane & 15, lk = lane >> 4;
  int cbase = wid * 128;
  f32x4 acc[8];
#pragma unroll
  for (int f = 0; f < 8; ++f) acc[f] = (f32x4){0.f, 0.f, 0.f, 0.f};
#pragma unroll
  for (int kk = 0; kk < 8; ++kk) {
    int ko = kk * 32 + lk * 8;
    short8v ahi = *(const short8v*)&Ahi[lr][ko];
    short8v alo = *(const short8v*)&Alo[lr][ko];
#pragma unroll
    for (int f = 0; f < 8; ++f) {
      size_t cc = (size_t)(cbase + f * 16 + lr);
      short8v bhi = *(const short8v*)(wthi + cc * 256 + ko);
      short8v blo = *(const short8v*)(wtlo + cc * 256 + ko);
      acc[f] = __builtin_amdgcn_mfma_f32_16x16x32_bf16(ahi, bhi, acc[f], 0, 0, 0);
      acc[f] = __builtin_amdgcn_mfma_f32_16x16x32_bf16(ahi, blo, acc[f], 0, 0, 0);
      acc[f] = __builtin_amdgcn_mfma_f32_16x16x32_bf16(alo, bhi, acc[f], 0, 0, 0);
    }
  }
#pragma unroll
  for (int f = 0; f < 8; ++f) {
    int cc = cbase + f * 16 + lr;
    float* outp = (cc < 256) ? (xlo_ + cc) : (xro_ + (cc - 256));
#pragma unroll
    for (int j = 0; j < 4; ++j)
      outp[(size_t)(r0 + lk * 4 + j) * 256] = acc[f][j];
  }
}

// ---------------- fused GATv2 layer: 1 wave = 1 node, We pinned in VGPRs ----------------
// EXACT R13 configuration (empirical optimum 117 µs): batch-4 online softmax, TERNARY
// leaky (R16: fmaxf variant regressed to 130 µs / +55% VALU issue — codegen artifact).
__global__ __launch_bounds__(64, 4) void gat_kernel(const float* __restrict__ xl,
                                                    const float* __restrict__ xr,
                                                    const int* __restrict__ esrc,
                                                    const float* __restrict__ eac,
                                                    const int* __restrict__ esort,
                                                    const int* __restrict__ src,
                                                    const float* __restrict__ ea,
                                                    const int* __restrict__ rowptr,
                                                    const float* __restrict__ We,
                                                    const float* __restrict__ att,
                                                    const float* __restrict__ bc,
                                                    float* __restrict__ hout, int n) {
  int lane = threadIdx.x;
  int node = blockIdx.x;
  if (node >= n) return;
  int c = lane * 4;
  size_t nb = (size_t)node * HD;
  float4 bc4 = *(const float4*)(bc + c);
  int pbeg = rowptr[node], pend = rowptr[node + 1];
  int deg = pend - pbeg;
  if (deg == 0) { *(float4*)(hout + nb + c) = bc4; return; }

  float4 w4[16];
#pragma unroll
  for (int k = 0; k < 16; ++k) w4[k] = *(const float4*)(We + k * HD + c);
  // pin We slice in VGPRs: opaque to the compiler -> cannot rematerialize/reload
#pragma unroll
  for (int k = 0; k < 16; ++k)
    asm volatile("" : "+v"(w4[k].x), "+v"(w4[k].y), "+v"(w4[k].z), "+v"(w4[k].w));

  float4 att4 = *(const float4*)(att + c);
  float4 xr4 = *(const float4*)(xr + nb + c);
  float4 acc = make_float4(0.f, 0.f, 0.f, 0.f);
  float m = -3.0e38f, d = 0.f;

  if (deg <= 64) {
    int es = (lane < deg) ? esrc[pbeg + lane] : 0;
    for (int b = 0; b < deg; b += 4) {
      int nbt = min(4, deg - b);
      float4 xv[4];
#pragma unroll
      for (int i = 0; i < 4; ++i) {
        if (i < nbt) {
          int si = __builtin_amdgcn_readfirstlane(__shfl(es, b + i));
          xv[i] = *(const float4*)(xl + (size_t)si * HD + c);
        }
      }
#pragma unroll
      for (int i = 0; i < 4; ++i) {
        if (i < nbt) {
          const float* ear = eac + (size_t)(pbeg + b + i) * 16;  // uniform -> s_load
          float4 v;
          v.x = xv[i].x + xr4.x;
          v.y = xv[i].y + xr4.y;
          v.z = xv[i].z + xr4.z;
          v.w = xv[i].w + xr4.w;
#pragma unroll
          for (int k = 0; k < 16; ++k) {
            float av = ear[k];
            v.x += av * w4[k].x;
            v.y += av * w4[k].y;
            v.z += av * w4[k].z;
            v.w += av * w4[k].w;
          }
          float l0 = v.x > 0.f ? v.x : NEG * v.x;
          float l1 = v.y > 0.f ? v.y : NEG * v.y;
          float l2 = v.z > 0.f ? v.z : NEG * v.z;
          float l3 = v.w > 0.f ? v.w : NEG * v.w;
          float pv = l0 * att4.x + l1 * att4.y + l2 * att4.z + l3 * att4.w;
          pv += __shfl_xor(pv, 16);
          pv += __shfl_xor(pv, 8);
          pv += __shfl_xor(pv, 4);
          pv += __shfl_xor(pv, 2);
          pv += __shfl_xor(pv, 1);
          float rs, pe;
          if (pv > m) { rs = __expf(m - pv); m = pv; pe = 1.f; }
          else        { rs = 1.f; pe = __expf(pv - m); }
          d = d * rs + pe;
          acc.x = acc.x * rs + pe * xv[i].x;
          acc.y = acc.y * rs + pe * xv[i].y;
          acc.z = acc.z * rs + pe * xv[i].z;
          acc.w = acc.w * rs + pe * xv[i].w;
        }
      }
    }
  } else {
    // deterministic fallback (deg>64, ~never): ascending-edge-id online softmax
    int last = -1;
    for (int r = 0; r < deg; ++r) {
      int mymin = 0x7fffffff;
      for (int p = pbeg + lane; p < pend; p += 64) {
        int v = esort[p];
        mymin = (v > last && v < mymin) ? v : mymin;
      }
#pragma unroll
      for (int off = 32; off >= 1; off >>= 1) {
        int u = __shfl_xor(mymin, off);
        mymin = min(mymin, u);
      }
      int e = __builtin_amdgcn_readfirstlane(mymin);
      last = e;
      int s = __builtin_amdgcn_readfirstlane(src[e]);
      float4 xv = *(const float4*)(xl + (size_t)s * HD + c);
      const float* ear = ea + (size_t)e * 16;
      float4 v;
      v.x = xv.x + xr4.x; v.y = xv.y + xr4.y; v.z = xv.z + xr4.z; v.w = xv.w + xr4.w;
#pragma unroll
      for (int k = 0; k < 16; ++k) {
        float av = ear[k];
        v.x += av * w4[k].x;
        v.y += av * w4[k].y;
        v.z += av * w4[k].z;
        v.w += av * w4[k].w;
      }
      float l0 = v.x > 0.f ? v.x : NEG * v.x;
      float l1 = v.y > 0.f ? v.y : NEG * v.y;
      float l2 = v.z > 0.f ? v.z : NEG * v.z;
      float l3 = v.w > 0.f ? v.w : NEG * v.w;
      float pv = l0 * att4.x + l1 * att4.y + l2 * att4.z + l3 * att4.w;
      pv += __shfl_xor(pv, 16);
      pv += __shfl_xor(pv, 8);
      pv += __shfl_xor(pv, 4);
      pv += __shfl_xor(pv, 2);
      pv += __shfl_xor(pv, 1);
      float rs, pe;
      if (pv > m) { rs = __expf(m - pv); m = pv; pe = 1.f; }
      else        { rs = 1.f; pe = __expf(pv - m); }
      d = d * rs + pe;
      acc.x = acc.x * rs + pe * xv.x;
      acc.y = acc.y * rs + pe * xv.y;
      acc.z = acc.z * rs + pe * xv.z;
      acc.w = acc.w * rs + pe * xv.w;
    }
  }
  float inv = d > 0.f ? 1.f / d : 0.f;
  float4 o;
  o.x = acc.x * inv + bc4.x;
  o.y = acc.y * inv + bc4.y;
  o.z = acc.z * inv + bc4.z;
  o.w = acc.w * inv + bc4.w;
  *(float4*)(hout + nb + c) = o;
}

// ---------------- deterministic BN partials ----------------
__global__ __launch_bounds__(256) void bn_stats(const float* __restrict__ h,
                                                float* __restrict__ partials, int n) {
  int c = threadIdx.x;
  int g = blockIdx.x;
  int rows = (n + GSTAT - 1) / GSTAT;
  int r0 = g * rows;
  int r1 = min(n, r0 + rows);
  float s = 0.f, s2 = 0.f;
  for (int r = r0; r < r1; ++r) {
    float v = h[(size_t)r * HD + c];
    s += v;
    s2 += v * v;
  }
  partials[g * 512 + c] = s;
  partials[g * 512 + 256 + c] = s2;
}

// ---------------- fused head: BN+ReLU + mean-pool + 3-layer MLP ----------------
__global__ __launch_bounds__(256) void head_kernel(const float* __restrict__ h,
                                                   const float* __restrict__ partials,
                                                   const float* __restrict__ gamma,
                                                   const float* __restrict__ beta,
                                                   const int* __restrict__ batch,
                                                   const float* __restrict__ gf,
                                                   const float* __restrict__ W1,
                                                   const float* __restrict__ b1,
                                                   const float* __restrict__ W2,
                                                   const float* __restrict__ b2,
                                                   const float* __restrict__ W3,
                                                   const float* __restrict__ b3,
                                                   float* __restrict__ out, int n, float nf) {
  int b = blockIdx.x, t = threadIdx.x;
  float s = 0.f, s2 = 0.f;
  for (int g = 0; g < GSTAT; ++g) {
    s += partials[g * 512 + t];
    s2 += partials[g * 512 + 256 + t];
  }
  float mean = s / nf;
  float var = s2 / nf - mean * mean;
  float sc = gamma[t] * rsqrtf(var + BN_EPS);
  float sh = beta[t] - mean * sc;

  int lo = 0, hi = n;
  while (lo < hi) { int mid = (lo + hi) >> 1; if (batch[mid] < b) lo = mid + 1; else hi = mid; }
  int s0 = lo;
  lo = 0; hi = n;
  while (lo < hi) { int mid = (lo + hi) >> 1; if (batch[mid] < b + 1) lo = mid + 1; else hi = mid; }
  int s1 = lo;

  float acc = 0.f;
  for (int r = s0; r < s1; ++r) acc += fmaxf(h[(size_t)r * HD + t] * sc + sh, 0.f);

  __shared__ float in_s[264];
  __shared__ float z1s[256];
  __shared__ float z2s[128];
  float cnt = (float)(s1 - s0);
  in_s[t] = (s1 > s0) ? acc / cnt : 0.f;
  if (t < 8) in_s[HD + t] = gf[b * 8 + t];
  __syncthreads();
  float z = b1[t];
  for (int k = 0; k < 264; ++k) z += in_s[k] * W1[(size_t)k * 256 + t];
  z1s[t] = fmaxf(z, 0.f);
  __syncthreads();
  if (t < 128) {
    float a2 = b2[t];
    for (int k = 0; k < 256; ++k) a2 += z1s[k] * W2[k * 128 + t];
    z2s[t] = fmaxf(a2, 0.f);
  }
  __syncthreads();
  if (t < 100) {
    float o = b3[t];
    for (int k = 0; k < 128; ++k) o += z2s[k] * W3[k * 100 + t];
    out[b * 100 + t] = o;
  }
}

extern "C" void kernel_launch(void* const* d_in, const int* in_sizes, int n_in,
                              void* d_out, int out_size, void* d_ws, size_t ws_size,
                              hipStream_t stream) {
  (void)n_in; (void)out_size; (void)ws_size;
  const float* x      = (const float*)d_in[0];
  const int*   ei     = (const int*)d_in[1];
  const float* ea     = (const float*)d_in[2];
  const int*   batch  = (const int*)d_in[3];
  const float* gf     = (const float*)d_in[4];
  const int E = in_sizes[1] / 2;
  const int N = in_sizes[3];
  const int B = in_sizes[4] / 8;
  const int* srcA = ei;
  const int* dstA = ei + E;

  const float *Wl[3], *Wr[3], *We[3], *att[3], *bc[3], *gamma[3], *beta[3];
  for (int l = 0; l < 3; ++l) {
    int base = 5 + 7 * l;
    Wl[l]    = (const float*)d_in[base + 0];
    Wr[l]    = (const float*)d_in[base + 1];
    We[l]    = (const float*)d_in[base + 2];
    att[l]   = (const float*)d_in[base + 3];
    bc[l]    = (const float*)d_in[base + 4];
    gamma[l] = (const float*)d_in[base + 5];
    beta[l]  = (const float*)d_in[base + 6];
  }
  const float* W1 = (const float*)d_in[26];
  const float* b1 = (const float*)d_in[27];
  const float* W2 = (const float*)d_in[28];
  const float* b2 = (const float*)d_in[29];
  const float* W3 = (const float*)d_in[30];
  const float* b3 = (const float*)d_in[31];

  char* w = (char*)d_ws;
  size_t off = 0;
  auto A = [&](size_t bytes) { size_t o = off; off = (off + bytes + 255) & ~(size_t)255; return o; };
  int*    rowptr   = (int*)(w + A((size_t)(N + 1) * 4));
  int*    fill     = (int*)(w + A((size_t)2 * N * 4));
  int*    esort    = (int*)(w + A((size_t)E * 4));
  int*    esrc     = (int*)(w + A((size_t)E * 4));
  float*  eac      = (float*)(w + A((size_t)E * 16 * 4));
  float*  hbuf     = (float*)(w + A((size_t)N * HD * 4));
  float*  xlb      = (float*)(w + A((size_t)N * HD * 4));
  float*  xrb      = (float*)(w + A((size_t)N * HD * 4));
  float*  partials = (float*)(w + A((size_t)GSTAT * 512 * 4));
  float*  bnss     = (float*)(w + A(512 * 4));
  ushort* wthi[2], *wtlo[2];
  for (int l = 0; l < 2; ++l) {
    wthi[l] = (ushort*)(w + A(512 * 256 * 2));
    wtlo[l] = (ushort*)(w + A(512 * 256 * 2));
  }

  // CSR by dst; per-node order fixed by csr_finish sort
  hipMemsetAsync(fill, 0, (size_t)2 * N * 4, stream);
  hist_kernel<<<(E + 255) / 256, 256, 0, stream>>>(dstA, fill, E);
  scan_kernel<<<1, 1024, 0, stream>>>(fill, rowptr, N);
  scatter_kernel<<<(E + 255) / 256, 256, 0, stream>>>(dstA, rowptr, fill + N, esort, E);
  csr_finish<<<(N + 3) / 4, 256, 0, stream>>>(srcA, rowptr, esort, ea, esrc, eac, N);
  // weight split+transpose for MFMA layers (independent of h)
  split_w<<<512, 256, 0, stream>>>(Wl[1], Wr[1], wthi[0], wtlo[0]);
  split_w<<<512, 256, 0, stream>>>(Wl[2], Wr[2], wthi[1], wtlo[1]);

  for (int l = 0; l < 3; ++l) {
    if (l == 0) {
      gemm_dual6<<<(N + 31) / 32, 256, 0, stream>>>(x, Wl[0], Wr[0], xlb, xrb, N);
    } else {
      bn_finalize<<<1, 256, 0, stream>>>(partials, gamma[l - 1], beta[l - 1], bnss, (float)N);
      gemm_mfma<<<(N + 15) / 16, 256, 0, stream>>>(hbuf, bnss, wthi[l - 1], wtlo[l - 1],
                                                   xlb, xrb, N);
    }
    gat_kernel<<<N, 64, 0, stream>>>(xlb, xrb, esrc, eac, esort, srcA, ea, rowptr,
                                     We[l], att[l], bc[l], hbuf, N);
    bn_stats<<<GSTAT, 256, 0, stream>>>(hbuf, partials, N);
  }

  head_kernel<<<B, 256, 0, stream>>>(hbuf, partials, gamma[2], beta[2], batch, gf,
                                     W1, b1, W2, b2, W3, b3, (float*)d_out, N, (float)N);
}

// Round 19
// 708.482 us; speedup vs baseline: 1.1650x; 1.0826x over previous
//
#include <hip/hip_runtime.h>
#include <math.h>

#define HD 256
#define NEG 0.2f
#define BN_EPS 1e-5f
#define GSTAT 256  // deterministic BN partial blocks
#define APAD 8
#define PCH 8      // pool chunks per graph

typedef __attribute__((ext_vector_type(8))) short short8v;   // 8 bf16 (4 VGPRs)
typedef __attribute__((ext_vector_type(4))) float f32x4;     // MFMA accumulator

__device__ __forceinline__ ushort bf16_rn(float x) {
  unsigned u = __float_as_uint(x);
  return (ushort)((u + 0x7FFFu + ((u >> 16) & 1u)) >> 16);
}
__device__ __forceinline__ float bf16_to_f(ushort b) {
  return __uint_as_float(((unsigned)b) << 16);
}

// ---------------- CSR build (by dst) ----------------
__global__ void hist_kernel(const int* __restrict__ dst, int* __restrict__ cnt, int E) {
  int i = blockIdx.x * blockDim.x + threadIdx.x;
  if (i < E) atomicAdd(&cnt[dst[i]], 1);
}

__global__ __launch_bounds__(1024) void scan_kernel(const int* __restrict__ cnt,
                                                    int* __restrict__ rowptr, int n) {
  __shared__ int sdata[1024];
  int t = threadIdx.x;
  int ipt = (n + 1023) >> 10;
  int base = t * ipt;
  int s = 0;
  for (int i = 0; i < ipt; ++i) { int idx = base + i; if (idx < n) s += cnt[idx]; }
  sdata[t] = s;
  __syncthreads();
  for (int off = 1; off < 1024; off <<= 1) {
    int v = (t >= off) ? sdata[t - off] : 0;
    __syncthreads();
    sdata[t] += v;
    __syncthreads();
  }
  int run = (t == 0) ? 0 : sdata[t - 1];
  for (int i = 0; i < ipt; ++i) {
    int idx = base + i;
    if (idx < n) { run += cnt[idx]; rowptr[idx + 1] = run; }
  }
  if (t == 0) rowptr[0] = 0;
}

__global__ void scatter_kernel(const int* __restrict__ dst, const int* __restrict__ rowptr,
                               int* __restrict__ fill, int* __restrict__ esort, int E) {
  int i = blockIdx.x * blockDim.x + threadIdx.x;
  if (i < E) {
    int d = dst[i];
    int pos = atomicAdd(&fill[d], 1);
    esort[rowptr[d] + pos] = i;
  }
}

// ---------------- per-node sort + CSR-ordered index/edge-attr materialization ----------------
__global__ __launch_bounds__(256) void csr_finish(const int* __restrict__ src,
                                                  const int* __restrict__ rowptr,
                                                  const int* __restrict__ esort,
                                                  const float* __restrict__ ea,
                                                  int* __restrict__ esrc,
                                                  float* __restrict__ eac, int n) {
  int t = threadIdx.x;
  int lane = t & 63;
  int node = __builtin_amdgcn_readfirstlane(blockIdx.x * 4 + (t >> 6));
  if (node >= n) return;
  int pbeg = rowptr[node], pend = rowptr[node + 1];
  int deg = pend - pbeg;
  if (deg == 0 || deg > 64) return;
  int v = (lane < deg) ? esort[pbeg + lane] : 0x7fffffff;
#pragma unroll
  for (int k = 2; k <= 64; k <<= 1) {
#pragma unroll
    for (int j = k >> 1; j >= 1; j >>= 1) {
      int u = __shfl_xor(v, j);
      bool keepmin = (((lane & k) == 0) == ((lane & j) == 0));
      v = keepmin ? (v < u ? v : u) : (v > u ? v : u);
    }
  }
  if (lane < deg) {
    esrc[pbeg + lane] = src[v];
    const float4* s4 = (const float4*)(ea + (size_t)v * 16);
    float4* d4 = (float4*)(eac + (size_t)(pbeg + lane) * 16);
    d4[0] = s4[0]; d4[1] = s4[1]; d4[2] = s4[2]; d4[3] = s4[3];
  }
}

// ---------------- dual GEMM K=6 (layer 0) ----------------
__global__ __launch_bounds__(256) void gemm_dual6(const float* __restrict__ h,
                                                  const float* __restrict__ Wl,
                                                  const float* __restrict__ Wr,
                                                  float* __restrict__ xlo, float* __restrict__ xro,
                                                  int n) {
  __shared__ float hs[32 * 6];
  int r0 = blockIdx.x * 32;
  int t = threadIdx.x;
  int nr = min(32, n - r0);
  int tot = nr * 6;
  for (int i = t; i < tot; i += 256) hs[i] = h[(size_t)r0 * 6 + i];
  __syncthreads();
  float accl[32], accr[32];
#pragma unroll
  for (int r = 0; r < 32; ++r) { accl[r] = 0.f; accr[r] = 0.f; }
  int j = t;
  for (int k = 0; k < 6; ++k) {
    float wl = Wl[k * HD + j];
    float wr = Wr[k * HD + j];
#pragma unroll
    for (int r = 0; r < 32; ++r) {
      float hv = hs[r * 6 + k];
      accl[r] += hv * wl;
      accr[r] += hv * wr;
    }
  }
  for (int r = 0; r < nr; ++r) {
    xlo[(size_t)(r0 + r) * HD + j] = accl[r];
    xro[(size_t)(r0 + r) * HD + j] = accr[r];
  }
}

// ---------------- weight split+transpose (once per layer): Wt[j][k] hi/lo bf16 ----------------
__global__ __launch_bounds__(256) void split_w(const float* __restrict__ Wl,
                                               const float* __restrict__ Wr,
                                               ushort* __restrict__ wthi,
                                               ushort* __restrict__ wtlo) {
  int idx = blockIdx.x * 256 + threadIdx.x;  // 512*256
  int j = idx >> 8;
  int k = idx & 255;
  float v = (j < 256) ? Wl[k * 256 + j] : Wr[k * 256 + (j - 256)];
  ushort hi = bf16_rn(v);
  float lo = v - bf16_to_f(hi);
  wthi[idx] = hi;
  wtlo[idx] = bf16_rn(lo);
}

// ---------------- BN finalize (deterministic, 1 block) ----------------
__global__ void bn_finalize(const float* __restrict__ partials, const float* __restrict__ gamma,
                            const float* __restrict__ beta, float* __restrict__ ss, float nf) {
  int c = threadIdx.x;
  float s = 0.f, s2 = 0.f;
  for (int g = 0; g < GSTAT; ++g) {
    s += partials[g * 512 + c];
    s2 += partials[g * 512 + 256 + c];
  }
  float mean = s / nf;
  float var = s2 / nf - mean * mean;
  float sc = gamma[c] * rsqrtf(var + BN_EPS);
  ss[c] = sc;
  ss[256 + c] = beta[c] - mean * sc;
}

// ---------------- MFMA GEMM, full-N tile, fused BN+ReLU+split on A staging ----------------
__global__ __launch_bounds__(256) void gemm_mfma(const float* __restrict__ h,
                                                 const float* __restrict__ ss,
                                                 const ushort* __restrict__ wthi,
                                                 const ushort* __restrict__ wtlo,
                                                 float* __restrict__ xlo_,
                                                 float* __restrict__ xro_, int n) {
  __shared__ ushort Ahi[16][256 + APAD];
  __shared__ ushort Alo[16][256 + APAD];
  int t = threadIdx.x;
  int r0 = blockIdx.x * 16;
  if (r0 >= n) return;
  {
    const float4* gsrc = (const float4*)(h + (size_t)r0 * 256);
    for (int i = t; i < 1024; i += 256) {
      int row = i >> 6, c4 = (i & 63) * 4;
      float4 v = gsrc[i];
      float a0 = fmaxf(v.x * ss[c4 + 0] + ss[256 + c4 + 0], 0.f);
      float a1 = fmaxf(v.y * ss[c4 + 1] + ss[256 + c4 + 1], 0.f);
      float a2 = fmaxf(v.z * ss[c4 + 2] + ss[256 + c4 + 2], 0.f);
      float a3 = fmaxf(v.w * ss[c4 + 3] + ss[256 + c4 + 3], 0.f);
      ushort4 hi, lo;
      hi.x = bf16_rn(a0); lo.x = bf16_rn(a0 - bf16_to_f(hi.x));
      hi.y = bf16_rn(a1); lo.y = bf16_rn(a1 - bf16_to_f(hi.y));
      hi.z = bf16_rn(a2); lo.z = bf16_rn(a2 - bf16_to_f(hi.z));
      hi.w = bf16_rn(a3); lo.w = bf16_rn(a3 - bf16_to_f(hi.w));
      *(ushort4*)&Ahi[row][c4] = hi;
      *(ushort4*)&Alo[row][c4] = lo;
    }
  }
  __syncthreads();
  int wid = t >> 6, lane = t & 63;
  int lr = lane & 15, lk = lane >> 4;
  int cbase = wid * 128;
  f32x4 acc[8];
#pragma unroll
  for (int f = 0; f < 8; ++f) acc[f] = (f32x4){0.f, 0.f, 0.f, 0.f};
#pragma unroll
  for (int kk = 0; kk < 8; ++kk) {
    int ko = kk * 32 + lk * 8;
    short8v ahi = *(const short8v*)&Ahi[lr][ko];
    short8v alo = *(const short8v*)&Alo[lr][ko];
#pragma unroll
    for (int f = 0; f < 8; ++f) {
      size_t cc = (size_t)(cbase + f * 16 + lr);
      short8v bhi = *(const short8v*)(wthi + cc * 256 + ko);
      short8v blo = *(const short8v*)(wtlo + cc * 256 + ko);
      acc[f] = __builtin_amdgcn_mfma_f32_16x16x32_bf16(ahi, bhi, acc[f], 0, 0, 0);
      acc[f] = __builtin_amdgcn_mfma_f32_16x16x32_bf16(ahi, blo, acc[f], 0, 0, 0);
      acc[f] = __builtin_amdgcn_mfma_f32_16x16x32_bf16(alo, bhi, acc[f], 0, 0, 0);
    }
  }
#pragma unroll
  for (int f = 0; f < 8; ++f) {
    int cc = cbase + f * 16 + lr;
    float* outp = (cc < 256) ? (xlo_ + cc) : (xro_ + (cc - 256));
#pragma unroll
    for (int j = 0; j < 4; ++j)
      outp[(size_t)(r0 + lk * 4 + j) * 256] = acc[f][j];
  }
}

// ---------------- fused GATv2 layer: 1 wave = 1 node, We pinned in VGPRs ----------------
// EXACT R13 configuration (empirical optimum 117 µs): batch-4 online softmax, TERNARY leaky.
__global__ __launch_bounds__(64, 4) void gat_kernel(const float* __restrict__ xl,
                                                    const float* __restrict__ xr,
                                                    const int* __restrict__ esrc,
                                                    const float* __restrict__ eac,
                                                    const int* __restrict__ esort,
                                                    const int* __restrict__ src,
                                                    const float* __restrict__ ea,
                                                    const int* __restrict__ rowptr,
                                                    const float* __restrict__ We,
                                                    const float* __restrict__ att,
                                                    const float* __restrict__ bc,
                                                    float* __restrict__ hout, int n) {
  int lane = threadIdx.x;
  int node = blockIdx.x;
  if (node >= n) return;
  int c = lane * 4;
  size_t nb = (size_t)node * HD;
  float4 bc4 = *(const float4*)(bc + c);
  int pbeg = rowptr[node], pend = rowptr[node + 1];
  int deg = pend - pbeg;
  if (deg == 0) { *(float4*)(hout + nb + c) = bc4; return; }

  float4 w4[16];
#pragma unroll
  for (int k = 0; k < 16; ++k) w4[k] = *(const float4*)(We + k * HD + c);
#pragma unroll
  for (int k = 0; k < 16; ++k)
    asm volatile("" : "+v"(w4[k].x), "+v"(w4[k].y), "+v"(w4[k].z), "+v"(w4[k].w));

  float4 att4 = *(const float4*)(att + c);
  float4 xr4 = *(const float4*)(xr + nb + c);
  float4 acc = make_float4(0.f, 0.f, 0.f, 0.f);
  float m = -3.0e38f, d = 0.f;

  if (deg <= 64) {
    int es = (lane < deg) ? esrc[pbeg + lane] : 0;
    for (int b = 0; b < deg; b += 4) {
      int nbt = min(4, deg - b);
      float4 xv[4];
#pragma unroll
      for (int i = 0; i < 4; ++i) {
        if (i < nbt) {
          int si = __builtin_amdgcn_readfirstlane(__shfl(es, b + i));
          xv[i] = *(const float4*)(xl + (size_t)si * HD + c);
        }
      }
#pragma unroll
      for (int i = 0; i < 4; ++i) {
        if (i < nbt) {
          const float* ear = eac + (size_t)(pbeg + b + i) * 16;  // uniform -> s_load
          float4 v;
          v.x = xv[i].x + xr4.x;
          v.y = xv[i].y + xr4.y;
          v.z = xv[i].z + xr4.z;
          v.w = xv[i].w + xr4.w;
#pragma unroll
          for (int k = 0; k < 16; ++k) {
            float av = ear[k];
            v.x += av * w4[k].x;
            v.y += av * w4[k].y;
            v.z += av * w4[k].z;
            v.w += av * w4[k].w;
          }
          float l0 = v.x > 0.f ? v.x : NEG * v.x;
          float l1 = v.y > 0.f ? v.y : NEG * v.y;
          float l2 = v.z > 0.f ? v.z : NEG * v.z;
          float l3 = v.w > 0.f ? v.w : NEG * v.w;
          float pv = l0 * att4.x + l1 * att4.y + l2 * att4.z + l3 * att4.w;
          pv += __shfl_xor(pv, 16);
          pv += __shfl_xor(pv, 8);
          pv += __shfl_xor(pv, 4);
          pv += __shfl_xor(pv, 2);
          pv += __shfl_xor(pv, 1);
          float rs, pe;
          if (pv > m) { rs = __expf(m - pv); m = pv; pe = 1.f; }
          else        { rs = 1.f; pe = __expf(pv - m); }
          d = d * rs + pe;
          acc.x = acc.x * rs + pe * xv[i].x;
          acc.y = acc.y * rs + pe * xv[i].y;
          acc.z = acc.z * rs + pe * xv[i].z;
          acc.w = acc.w * rs + pe * xv[i].w;
        }
      }
    }
  } else {
    // deterministic fallback (deg>64, ~never): ascending-edge-id online softmax
    int last = -1;
    for (int r = 0; r < deg; ++r) {
      int mymin = 0x7fffffff;
      for (int p = pbeg + lane; p < pend; p += 64) {
        int v = esort[p];
        mymin = (v > last && v < mymin) ? v : mymin;
      }
#pragma unroll
      for (int off = 32; off >= 1; off >>= 1) {
        int u = __shfl_xor(mymin, off);
        mymin = min(mymin, u);
      }
      int e = __builtin_amdgcn_readfirstlane(mymin);
      last = e;
      int s = __builtin_amdgcn_readfirstlane(src[e]);
      float4 xv = *(const float4*)(xl + (size_t)s * HD + c);
      const float* ear = ea + (size_t)e * 16;
      float4 v;
      v.x = xv.x + xr4.x; v.y = xv.y + xr4.y; v.z = xv.z + xr4.z; v.w = xv.w + xr4.w;
#pragma unroll
      for (int k = 0; k < 16; ++k) {
        float av = ear[k];
        v.x += av * w4[k].x;
        v.y += av * w4[k].y;
        v.z += av * w4[k].z;
        v.w += av * w4[k].w;
      }
      float l0 = v.x > 0.f ? v.x : NEG * v.x;
      float l1 = v.y > 0.f ? v.y : NEG * v.y;
      float l2 = v.z > 0.f ? v.z : NEG * v.z;
      float l3 = v.w > 0.f ? v.w : NEG * v.w;
      float pv = l0 * att4.x + l1 * att4.y + l2 * att4.z + l3 * att4.w;
      pv += __shfl_xor(pv, 16);
      pv += __shfl_xor(pv, 8);
      pv += __shfl_xor(pv, 4);
      pv += __shfl_xor(pv, 2);
      pv += __shfl_xor(pv, 1);
      float rs, pe;
      if (pv > m) { rs = __expf(m - pv); m = pv; pe = 1.f; }
      else        { rs = 1.f; pe = __expf(pv - m); }
      d = d * rs + pe;
      acc.x = acc.x * rs + pe * xv.x;
      acc.y = acc.y * rs + pe * xv.y;
      acc.z = acc.z * rs + pe * xv.z;
      acc.w = acc.w * rs + pe * xv.w;
    }
  }
  float inv = d > 0.f ? 1.f / d : 0.f;
  float4 o;
  o.x = acc.x * inv + bc4.x;
  o.y = acc.y * inv + bc4.y;
  o.z = acc.z * inv + bc4.z;
  o.w = acc.w * inv + bc4.w;
  *(float4*)(hout + nb + c) = o;
}

// ---------------- deterministic BN partials ----------------
__global__ __launch_bounds__(256) void bn_stats(const float* __restrict__ h,
                                                float* __restrict__ partials, int n) {
  int c = threadIdx.x;
  int g = blockIdx.x;
  int rows = (n + GSTAT - 1) / GSTAT;
  int r0 = g * rows;
  int r1 = min(n, r0 + rows);
  float s = 0.f, s2 = 0.f;
  for (int r = r0; r < r1; ++r) {
    float v = h[(size_t)r * HD + c];
    s += v;
    s2 += v * v;
  }
  partials[g * 512 + c] = s;
  partials[g * 512 + 256 + c] = s2;
}

// ---------------- pool partials: BN+ReLU + chunked per-graph sum (deterministic) ----------------
// grid = B * PCH; chunk c of graph b covers a fixed row range of [s0,s1).
__global__ __launch_bounds__(256) void pool_part(const float* __restrict__ h,
                                                 const float* __restrict__ ss,
                                                 const int* __restrict__ batch,
                                                 float* __restrict__ ppart, int n) {
  int b = blockIdx.x / PCH;
  int ch = blockIdx.x % PCH;
  int t = threadIdx.x;
  int lo = 0, hi = n;
  while (lo < hi) { int mid = (lo + hi) >> 1; if (batch[mid] < b) lo = mid + 1; else hi = mid; }
  int s0 = lo;
  lo = 0; hi = n;
  while (lo < hi) { int mid = (lo + hi) >> 1; if (batch[mid] < b + 1) lo = mid + 1; else hi = mid; }
  int s1 = lo;
  int len = s1 - s0;
  int r0 = s0 + (int)((long long)len * ch / PCH);
  int r1 = s0 + (int)((long long)len * (ch + 1) / PCH);
  float sc = ss[t], sh = ss[256 + t];
  float acc = 0.f;
  for (int r = r0; r < r1; ++r) acc += fmaxf(h[(size_t)r * HD + t] * sc + sh, 0.f);
  ppart[(size_t)blockIdx.x * HD + t] = acc;
}

// ---------------- head: reduce pool partials (fixed order) + 3-layer MLP ----------------
__global__ __launch_bounds__(256) void head_kernel(const float* __restrict__ ppart,
                                                   const int* __restrict__ batch,
                                                   const float* __restrict__ gf,
                                                   const float* __restrict__ W1,
                                                   const float* __restrict__ b1,
                                                   const float* __restrict__ W2,
                                                   const float* __restrict__ b2,
                                                   const float* __restrict__ W3,
                                                   const float* __restrict__ b3,
                                                   float* __restrict__ out, int n) {
  int b = blockIdx.x, t = threadIdx.x;
  int lo = 0, hi = n;
  while (lo < hi) { int mid = (lo + hi) >> 1; if (batch[mid] < b) lo = mid + 1; else hi = mid; }
  int s0 = lo;
  lo = 0; hi = n;
  while (lo < hi) { int mid = (lo + hi) >> 1; if (batch[mid] < b + 1) lo = mid + 1; else hi = mid; }
  int s1 = lo;
  float acc = 0.f;
#pragma unroll
  for (int ch = 0; ch < PCH; ++ch) acc += ppart[(size_t)(b * PCH + ch) * HD + t];

  __shared__ float in_s[264];
  __shared__ float z1s[256];
  __shared__ float z2s[128];
  float cnt = (float)(s1 - s0);
  in_s[t] = (s1 > s0) ? acc / cnt : 0.f;
  if (t < 8) in_s[HD + t] = gf[b * 8 + t];
  __syncthreads();
  float z = b1[t];
  for (int k = 0; k < 264; ++k) z += in_s[k] * W1[(size_t)k * 256 + t];
  z1s[t] = fmaxf(z, 0.f);
  __syncthreads();
  if (t < 128) {
    float a2 = b2[t];
    for (int k = 0; k < 256; ++k) a2 += z1s[k] * W2[k * 128 + t];
    z2s[t] = fmaxf(a2, 0.f);
  }
  __syncthreads();
  if (t < 100) {
    float o = b3[t];
    for (int k = 0; k < 128; ++k) o += z2s[k] * W3[k * 100 + t];
    out[b * 100 + t] = o;
  }
}

extern "C" void kernel_launch(void* const* d_in, const int* in_sizes, int n_in,
                              void* d_out, int out_size, void* d_ws, size_t ws_size,
                              hipStream_t stream) {
  (void)n_in; (void)out_size; (void)ws_size;
  const float* x      = (const float*)d_in[0];
  const int*   ei     = (const int*)d_in[1];
  const float* ea     = (const float*)d_in[2];
  const int*   batch  = (const int*)d_in[3];
  const float* gf     = (const float*)d_in[4];
  const int E = in_sizes[1] / 2;
  const int N = in_sizes[3];
  const int B = in_sizes[4] / 8;
  const int* srcA = ei;
  const int* dstA = ei + E;

  const float *Wl[3], *Wr[3], *We[3], *att[3], *bc[3], *gamma[3], *beta[3];
  for (int l = 0; l < 3; ++l) {
    int base = 5 + 7 * l;
    Wl[l]    = (const float*)d_in[base + 0];
    Wr[l]    = (const float*)d_in[base + 1];
    We[l]    = (const float*)d_in[base + 2];
    att[l]   = (const float*)d_in[base + 3];
    bc[l]    = (const float*)d_in[base + 4];
    gamma[l] = (const float*)d_in[base + 5];
    beta[l]  = (const float*)d_in[base + 6];
  }
  const float* W1 = (const float*)d_in[26];
  const float* b1 = (const float*)d_in[27];
  const float* W2 = (const float*)d_in[28];
  const float* b2 = (const float*)d_in[29];
  const float* W3 = (const float*)d_in[30];
  const float* b3 = (const float*)d_in[31];

  char* w = (char*)d_ws;
  size_t off = 0;
  auto A = [&](size_t bytes) { size_t o = off; off = (off + bytes + 255) & ~(size_t)255; return o; };
  int*    rowptr   = (int*)(w + A((size_t)(N + 1) * 4));
  int*    fill     = (int*)(w + A((size_t)2 * N * 4));
  int*    esort    = (int*)(w + A((size_t)E * 4));
  int*    esrc     = (int*)(w + A((size_t)E * 4));
  float*  eac      = (float*)(w + A((size_t)E * 16 * 4));
  float*  hbuf     = (float*)(w + A((size_t)N * HD * 4));
  float*  xlb      = (float*)(w + A((size_t)N * HD * 4));
  float*  xrb      = (float*)(w + A((size_t)N * HD * 4));
  float*  partials = (float*)(w + A((size_t)GSTAT * 512 * 4));
  float*  bnss     = (float*)(w + A(512 * 4));
  float*  ppart    = (float*)(w + A((size_t)B * PCH * HD * 4));
  ushort* wthi[2], *wtlo[2];
  for (int l = 0; l < 2; ++l) {
    wthi[l] = (ushort*)(w + A(512 * 256 * 2));
    wtlo[l] = (ushort*)(w + A(512 * 256 * 2));
  }

  // CSR by dst; per-node order fixed by csr_finish sort
  hipMemsetAsync(fill, 0, (size_t)2 * N * 4, stream);
  hist_kernel<<<(E + 255) / 256, 256, 0, stream>>>(dstA, fill, E);
  scan_kernel<<<1, 1024, 0, stream>>>(fill, rowptr, N);
  scatter_kernel<<<(E + 255) / 256, 256, 0, stream>>>(dstA, rowptr, fill + N, esort, E);
  csr_finish<<<(N + 3) / 4, 256, 0, stream>>>(srcA, rowptr, esort, ea, esrc, eac, N);
  // weight split+transpose for MFMA layers (independent of h)
  split_w<<<512, 256, 0, stream>>>(Wl[1], Wr[1], wthi[0], wtlo[0]);
  split_w<<<512, 256, 0, stream>>>(Wl[2], Wr[2], wthi[1], wtlo[1]);

  for (int l = 0; l < 3; ++l) {
    if (l == 0) {
      gemm_dual6<<<(N + 31) / 32, 256, 0, stream>>>(x, Wl[0], Wr[0], xlb, xrb, N);
    } else {
      bn_finalize<<<1, 256, 0, stream>>>(partials, gamma[l - 1], beta[l - 1], bnss, (float)N);
      gemm_mfma<<<(N + 15) / 16, 256, 0, stream>>>(hbuf, bnss, wthi[l - 1], wtlo[l - 1],
                                                   xlb, xrb, N);
    }
    gat_kernel<<<N, 64, 0, stream>>>(xlb, xrb, esrc, eac, esort, srcA, ea, rowptr,
                                     We[l], att[l], bc[l], hbuf, N);
    bn_stats<<<GSTAT, 256, 0, stream>>>(hbuf, partials, N);
  }

  // final-layer BN scale/shift, chunked deterministic pooling, then MLP head
  bn_finalize<<<1, 256, 0, stream>>>(partials, gamma[2], beta[2], bnss, (float)N);
  pool_part<<<B * PCH, 256, 0, stream>>>(hbuf, bnss, batch, ppart, N);
  head_kernel<<<B, 256, 0, stream>>>(ppart, batch, gf, W1, b1, W2, b2, W3, b3,
                                     (float*)d_out, N);
}